// Round 4
// baseline (1624.537 us; speedup 1.0000x reference)
//
#include <hip/hip_runtime.h>
#include <hip/hip_bf16.h>

#define D 64
#define BSHIFT 8           // 256 nodes per bucket
#define BNODES 256
#define PTILE 8192         // edges per partition tile (256 thr x 32)

// flags[0] = 1 if float tensors are fp32 (else bf16)
// flags[1] = 1 if edge_index is int64 (else int32)

__device__ __forceinline__ float bf16u_to_f32(unsigned short u) {
  union { unsigned int i; float f; } c;
  c.i = ((unsigned int)u) << 16;
  return c.f;
}

__global__ void k_probe(const void* W, const void* ei, int* flags) {
  if (threadIdx.x == 0 && blockIdx.x == 0) {
    const unsigned short* wb = (const unsigned short*)W;
    int big = 0;
    for (int i = 0; i < 512; i++) {
      float v = bf16u_to_f32(wb[i]);
      if (!(fabsf(v) < 100.f)) big = 1;  // NaN also lands here
    }
    flags[0] = big;  // huge magnitudes => data is actually fp32
    const int* e32 = (const int*)ei;
    int anynz = 0;
    for (int i = 1; i < 128; i += 2)
      if (e32[i] != 0) anynz = 1;
    flags[1] = anynz ? 0 : 1;  // all-zero odd slots => int64
  }
}

// ---------------- bucketed graph build ----------------

// global bucket histogram via LDS staging
__global__ __launch_bounds__(256) void k_hist(const void* __restrict__ ei,
                                              const int* __restrict__ flags,
                                              int* __restrict__ bucket_cnt,
                                              int e) {
  __shared__ int h[512];
  for (int b = threadIdx.x; b < 512; b += 256) h[b] = 0;
  __syncthreads();
  int i64 = flags[1];
  int i = blockIdx.x * 256 + threadIdx.x;
  int stride = gridDim.x * 256;
  if (i64) {
    const long long* dst = (const long long*)ei + e;
    for (; i < e; i += stride) atomicAdd(&h[((int)dst[i]) >> BSHIFT], 1);
  } else {
    const int* dst = (const int*)ei + e;
    for (; i < e; i += stride) atomicAdd(&h[dst[i] >> BSHIFT], 1);
  }
  __syncthreads();
  for (int b = threadIdx.x; b < 512; b += 256)
    if (h[b]) atomicAdd(&bucket_cnt[b], h[b]);
}

// single block of 512: exclusive scan -> bucket_base, init bucket_cursor
__global__ __launch_bounds__(512) void k_scan_buckets(
    const int* __restrict__ bucket_cnt, int* __restrict__ bucket_base,
    int* __restrict__ bucket_cursor, int nbuc, int e) {
  __shared__ int lds[512];
  int t = threadIdx.x;
  int v = (t < nbuc) ? bucket_cnt[t] : 0;
  lds[t] = v;
  __syncthreads();
  for (int off = 1; off < 512; off <<= 1) {
    int tv = (t >= off) ? lds[t - off] : 0;
    __syncthreads();
    lds[t] += tv;
    __syncthreads();
  }
  int base = lds[t] - v;  // exclusive
  if (t < nbuc) {
    bucket_base[t] = base;
    bucket_cursor[t] = base;
  }
  if (t == 0) bucket_base[nbuc] = e;
}

// LDS-staged partition: per tile, histogram -> reserve contiguous global runs
// (one atomic per tile x bucket) -> rank -> write packed (src<<8)|localdst.
// Write runs avg ~21 contiguous ints => ~1.3x line amplification (vs 16x for
// the old per-node atomic scatter).
__global__ __launch_bounds__(256) void k_partition(
    const void* __restrict__ ei, const int* __restrict__ flags,
    int* __restrict__ bucket_cursor, int* __restrict__ packed, int e) {
  __shared__ int lhist[512];
  __shared__ int lbase[512];
  int tid = threadIdx.x;
  int t0 = blockIdx.x * PTILE;
  int tend = min(t0 + PTILE, e);
  if (t0 >= e) return;
  int i64 = flags[1];

  for (int b = tid; b < 512; b += 256) lhist[b] = 0;
  __syncthreads();

  if (i64) {
    const long long* dst = (const long long*)ei + e;
    for (int i = t0 + tid; i < tend; i += 256)
      atomicAdd(&lhist[((int)dst[i]) >> BSHIFT], 1);
  } else {
    const int* dst = (const int*)ei + e;
    for (int i = t0 + tid; i < tend; i += 256)
      atomicAdd(&lhist[dst[i] >> BSHIFT], 1);
  }
  __syncthreads();

  for (int b = tid; b < 512; b += 256) {
    int c = lhist[b];
    lbase[b] = c ? atomicAdd(&bucket_cursor[b], c) : 0;
    lhist[b] = 0;  // reuse as rank counter
  }
  __syncthreads();

  if (i64) {
    const long long* srcp = (const long long*)ei;
    const long long* dstp = srcp + e;
    for (int i = t0 + tid; i < tend; i += 256) {
      int s = (int)srcp[i];
      int d = (int)dstp[i];
      int b = d >> BSHIFT;
      int r = atomicAdd(&lhist[b], 1);
      packed[lbase[b] + r] = (s << BSHIFT) | (d & (BNODES - 1));
    }
  } else {
    const int* srcp = (const int*)ei;
    const int* dstp = srcp + e;
    for (int i = t0 + tid; i < tend; i += 256) {
      int s = srcp[i];
      int d = dstp[i];
      int b = d >> BSHIFT;
      int r = atomicAdd(&lhist[b], 1);
      packed[lbase[b] + r] = (s << BSHIFT) | (d & (BNODES - 1));
    }
  }
}

// per-bucket degree count (LDS, no global atomics) -> dinv = rsqrt(deg+1)
__global__ __launch_bounds__(256) void k_deg_dinv(
    const int* __restrict__ packed, const int* __restrict__ bucket_base,
    float* __restrict__ dinv, int n) {
  __shared__ int cnt[BNODES];
  int tid = threadIdx.x;
  int bucket = blockIdx.x;
  int node0 = bucket << BSHIFT;
  int nodes = min(BNODES, n - node0);
  cnt[tid] = 0;
  __syncthreads();
  int s0 = bucket_base[bucket];
  int s1 = bucket_base[bucket + 1];
  for (int i = s0 + tid; i < s1; i += 256)
    atomicAdd(&cnt[packed[i] & (BNODES - 1)], 1);
  __syncthreads();
  if (tid < nodes) dinv[node0 + tid] = rsqrtf((float)(cnt[tid] + 1));
}

__global__ __launch_bounds__(256) void k_load_x(const void* __restrict__ in,
                                                const int* __restrict__ flags,
                                                float* __restrict__ out,
                                                int n) {
  int f32 = flags[0];
  int i = blockIdx.x * blockDim.x + threadIdx.x;
  int stride = gridDim.x * blockDim.x;
  if (f32) {
    const float* p = (const float*)in;
    for (; i < n; i += stride) out[i] = p[i];
  } else {
    const __hip_bfloat16* p = (const __hip_bfloat16*)in;
    for (; i < n; i += stride) out[i] = __bfloat162float(p[i]);
  }
}

// ---------------- compute kernels ----------------

// One wave per row (grid-strided). Lane j holds W[:,j] in 64 VGPRs; x-row
// address is wave-uniform (scalar loads). hp output bf16.
__global__ __launch_bounds__(256) void k_matmul2(
    const float* __restrict__ x, const void* __restrict__ Wb,
    const void* __restrict__ Wf, const float* __restrict__ dinv,
    __hip_bfloat16* __restrict__ outh, const int* __restrict__ flags,
    int nrows) {
  int f32 = flags[0];
  int lane = threadIdx.x & 63;
  int wid = threadIdx.x >> 6;
  float w[D];
  if (f32) {
    const float* W = (const float*)Wf;
#pragma unroll
    for (int k = 0; k < D; k++) w[k] = W[k * D + lane];
  } else {
    const __hip_bfloat16* W = (const __hip_bfloat16*)Wb;
#pragma unroll
    for (int k = 0; k < D; k++) w[k] = __bfloat162float(W[k * D + lane]);
  }

  int wave = blockIdx.x * 4 + wid;
  int nwaves = gridDim.x * 4;
  for (int row = wave; row < nrows; row += nwaves) {
    int ur = __builtin_amdgcn_readfirstlane(row);
    const float* xr = x + (size_t)ur * D;
    float a0 = 0.f, a1 = 0.f, a2 = 0.f, a3 = 0.f;
#pragma unroll
    for (int k = 0; k < D; k += 4) {
      a0 = fmaf(xr[k + 0], w[k + 0], a0);
      a1 = fmaf(xr[k + 1], w[k + 1], a1);
      a2 = fmaf(xr[k + 2], w[k + 2], a2);
      a3 = fmaf(xr[k + 3], w[k + 3], a3);
    }
    float acc = (a0 + a1) + (a2 + a3);
    outh[(size_t)ur * D + lane] = __float2bfloat16(dinv[ur] * acc);
  }
}

// Final projection: out = x@W + b, store dtype picked by flag.
__global__ __launch_bounds__(256) void k_matmul_final(
    const float* __restrict__ x, const void* __restrict__ W,
    const void* __restrict__ bias, void* __restrict__ out,
    const int* __restrict__ flags, int nrows) {
  int f32 = flags[0];
  int lane = threadIdx.x & 63;
  int wid = threadIdx.x >> 6;
  float w[D];
  float b;
  if (f32) {
    const float* Wf = (const float*)W;
#pragma unroll
    for (int k = 0; k < D; k++) w[k] = Wf[k * D + lane];
    b = ((const float*)bias)[lane];
  } else {
    const __hip_bfloat16* Wb = (const __hip_bfloat16*)W;
#pragma unroll
    for (int k = 0; k < D; k++) w[k] = __bfloat162float(Wb[k * D + lane]);
    b = __bfloat162float(((const __hip_bfloat16*)bias)[lane]);
  }

  int wave = blockIdx.x * 4 + wid;
  int nwaves = gridDim.x * 4;
  for (int row = wave; row < nrows; row += nwaves) {
    int ur = __builtin_amdgcn_readfirstlane(row);
    const float* xr = x + (size_t)ur * D;
    float a0 = 0.f, a1 = 0.f, a2 = 0.f, a3 = 0.f;
#pragma unroll
    for (int k = 0; k < D; k += 4) {
      a0 = fmaf(xr[k + 0], w[k + 0], a0);
      a1 = fmaf(xr[k + 1], w[k + 1], a1);
      a2 = fmaf(xr[k + 2], w[k + 2], a2);
      a3 = fmaf(xr[k + 3], w[k + 3], a3);
    }
    float r = (a0 + a1) + (a2 + a3) + b;
    size_t idx = (size_t)ur * D + lane;
    if (f32)
      ((float*)out)[idx] = r;
    else
      ((__hip_bfloat16*)out)[idx] = __float2bfloat16(r);
  }
}

// One block per bucket. acc[256][64] fp32 in LDS (64 KB). Init = self rows,
// then stream packed edges (scalar loads, 8 gathers in flight per wave),
// ds_add_f32 accumulate (bank-free: addr%32 == lane%32, 2-way). Finalize
// relu(dinv*acc + bias) with fully-coalesced fp32 writes.
__global__ __launch_bounds__(256) void k_agg_lds(
    const __hip_bfloat16* __restrict__ hp, const int* __restrict__ packed,
    const int* __restrict__ bucket_base, const float* __restrict__ dinv,
    const void* __restrict__ bias_b, const void* __restrict__ bias_f,
    const int* __restrict__ flags, float* __restrict__ xout, int n) {
  __shared__ float acc[BNODES * D];
  int tid = threadIdx.x;
  int bucket = blockIdx.x;
  int node0 = bucket << BSHIFT;
  int nodes = min(BNODES, n - node0);
  int cnt = nodes * D;
  const unsigned short* hpu = (const unsigned short*)hp;

  // self-loop init (coalesced)
  for (int i = tid; i < cnt; i += 256)
    acc[i] = bf16u_to_f32(hpu[(size_t)node0 * D + i]);
  __syncthreads();

  int s0 = bucket_base[bucket];
  int s1 = bucket_base[bucket + 1];
  int lane = tid & 63;
  int wid = tid >> 6;

  for (int base = s0 + wid * 8; base < s1; base += 32) {
    int m = min(8, s1 - base);
    int pk[8];
    float v[8];
#pragma unroll
    for (int u = 0; u < 8; u++) pk[u] = packed[(u < m) ? (base + u) : base];
#pragma unroll
    for (int u = 0; u < 8; u++) {
      int srcn = pk[u] >> BSHIFT;
      v[u] = bf16u_to_f32(hpu[(size_t)srcn * D + lane]);
    }
#pragma unroll
    for (int u = 0; u < 8; u++) {
      if (u < m) atomicAdd(&acc[(pk[u] & (BNODES - 1)) * D + lane], v[u]);
    }
  }
  __syncthreads();

  int f32 = flags[0];
  for (int i = tid; i < cnt; i += 256) {
    int nl = i >> 6;
    int f = i & 63;
    float b = f32 ? ((const float*)bias_f)[f]
                  : __bfloat162float(((const __hip_bfloat16*)bias_b)[f]);
    float r = fmaf(dinv[node0 + nl], acc[i], b);
    xout[(size_t)node0 * D + i] = fmaxf(r, 0.f);
  }
}

// ---------------- launch ----------------

extern "C" void kernel_launch(void* const* d_in, const int* in_sizes, int n_in,
                              void* d_out, int out_size, void* d_ws,
                              size_t ws_size, hipStream_t stream) {
  const void* x0 = d_in[0];
  const void* ei = d_in[1];
  const char* Ws = (const char*)d_in[2];
  const char* bs = (const char*)d_in[3];
  const void* Wout = d_in[4];
  const void* bout = d_in[5];

  const int N = in_sizes[0] / D;  // 100000
  const int E = in_sizes[1] / 2;  // 1000000
  const int NBUC = (N + BNODES - 1) >> BSHIFT;  // 391

  char* p = (char*)d_ws;
  auto alloc = [&](size_t bytes) {
    char* r = p;
    p += (bytes + 511) & ~(size_t)511;
    return r;
  };
  int* flags = (int*)alloc(8);
  int* bucket_cnt = (int*)alloc(512 * 4);
  int* bucket_base = (int*)alloc(513 * 4);
  int* bucket_cursor = (int*)alloc(512 * 4);
  int* packed = (int*)alloc((size_t)E * 4);
  float* dinv = (float*)alloc((size_t)N * 4);
  __hip_bfloat16* hp = (__hip_bfloat16*)alloc((size_t)N * D * 2);
  float* xbuf = (float*)alloc((size_t)N * D * 4);
  (void)ws_size;
  (void)n_in;
  (void)out_size;

  hipMemsetAsync(bucket_cnt, 0, 512 * 4, stream);

  k_probe<<<1, 64, 0, stream>>>(Ws, ei, flags);
  k_hist<<<512, 256, 0, stream>>>(ei, flags, bucket_cnt, E);
  k_scan_buckets<<<1, 512, 0, stream>>>(bucket_cnt, bucket_base, bucket_cursor,
                                        NBUC, E);
  int ptiles = (E + PTILE - 1) / PTILE;
  k_partition<<<ptiles, 256, 0, stream>>>(ei, flags, bucket_cursor, packed, E);
  k_deg_dinv<<<NBUC, 256, 0, stream>>>(packed, bucket_base, dinv, N);
  k_load_x<<<2048, 256, 0, stream>>>(x0, flags, xbuf, N * D);

  const size_t WSZ = (size_t)D * D;
  for (int l = 0; l < 3; ++l) {
    const void* W_b = Ws + (size_t)l * WSZ * 2;  // byte offset if bf16
    const void* W_f = Ws + (size_t)l * WSZ * 4;  // byte offset if fp32
    const void* b_b = bs + (size_t)l * D * 2;
    const void* b_f = bs + (size_t)l * D * 4;
    k_matmul2<<<1024, 256, 0, stream>>>(xbuf, W_b, W_f, dinv, hp, flags, N);
    k_agg_lds<<<NBUC, 256, 0, stream>>>(hp, packed, bucket_base, dinv, b_b,
                                        b_f, flags, xbuf, N);
  }
  k_matmul_final<<<1024, 256, 0, stream>>>(xbuf, Wout, bout, d_out, flags, N);
}

// Round 5
// 432.583 us; speedup vs baseline: 3.7554x; 3.7554x over previous
//
#include <hip/hip_runtime.h>
#include <hip/hip_bf16.h>

#define D 64
#define BSHIFT 8           // 256 nodes per bucket
#define BNODES 256
#define PTILE 8192         // edges per partition tile

// flags[0] = 1 if float tensors are fp32 (else bf16)
// flags[1] = 1 if edge_index is int64 (else int32)

__device__ __forceinline__ float bf16u_to_f32(unsigned short u) {
  union { unsigned int i; float f; } c;
  c.i = ((unsigned int)u) << 16;
  return c.f;
}

__device__ __forceinline__ unsigned short f32_to_bf16u(float f) {
  union { float f; unsigned int u; } c;
  c.f = f;
  unsigned int r = (c.u + 0x7fffu + ((c.u >> 16) & 1u)) >> 16;  // RNE
  return (unsigned short)r;
}

__global__ void k_probe(const void* W, const void* ei, int* flags) {
  int lane = threadIdx.x & 63;
  const unsigned short* wb = (const unsigned short*)W;
  bool big = false;
  for (int i = lane; i < 512; i += 64) {
    float v = bf16u_to_f32(wb[i]);
    if (!(fabsf(v) < 100.f)) big = true;  // NaN lands here too
  }
  int anybig = __any(big);
  const int* e32 = (const int*)ei;
  bool nz = (e32[2 * lane + 1] != 0);  // odd slots of first 64 pairs
  int anynz = __any(nz);
  if (threadIdx.x == 0) {
    flags[0] = anybig ? 1 : 0;  // huge magnitudes => data is actually fp32
    flags[1] = anynz ? 0 : 1;   // all-zero odd slots => int64
  }
}

// ---------------- bucketed graph build ----------------

__global__ __launch_bounds__(256) void k_hist(const void* __restrict__ ei,
                                              const int* __restrict__ flags,
                                              int* __restrict__ bucket_cnt,
                                              int e) {
  __shared__ int h[512];
  for (int b = threadIdx.x; b < 512; b += 256) h[b] = 0;
  __syncthreads();
  int i64 = flags[1];
  int i = blockIdx.x * 256 + threadIdx.x;
  int stride = gridDim.x * 256;
  if (i64) {
    const long long* dst = (const long long*)ei + e;
    for (; i < e; i += stride) atomicAdd(&h[((int)dst[i]) >> BSHIFT], 1);
  } else {
    const int* dst = (const int*)ei + e;
    for (; i < e; i += stride) atomicAdd(&h[dst[i] >> BSHIFT], 1);
  }
  __syncthreads();
  for (int b = threadIdx.x; b < 512; b += 256)
    if (h[b]) atomicAdd(&bucket_cnt[b], h[b]);
}

__global__ __launch_bounds__(512) void k_scan_buckets(
    const int* __restrict__ bucket_cnt, int* __restrict__ bucket_base,
    int* __restrict__ bucket_cursor, int nbuc, int e) {
  __shared__ int lds[512];
  int t = threadIdx.x;
  int v = (t < nbuc) ? bucket_cnt[t] : 0;
  lds[t] = v;
  __syncthreads();
  for (int off = 1; off < 512; off <<= 1) {
    int tv = (t >= off) ? lds[t - off] : 0;
    __syncthreads();
    lds[t] += tv;
    __syncthreads();
  }
  int base = lds[t] - v;  // exclusive
  if (t < nbuc) {
    bucket_base[t] = base;
    bucket_cursor[t] = base;
  }
  if (t == 0) bucket_base[nbuc] = e;
}

// LDS-staged partition: per tile, histogram -> one global atomic per
// (tile,bucket) reserving a contiguous run -> rank -> packed (src<<8)|ldst.
__global__ __launch_bounds__(256) void k_partition(
    const void* __restrict__ ei, const int* __restrict__ flags,
    int* __restrict__ bucket_cursor, int* __restrict__ packed, int e) {
  __shared__ int lhist[512];
  __shared__ int lbase[512];
  int tid = threadIdx.x;
  int t0 = blockIdx.x * PTILE;
  int tend = min(t0 + PTILE, e);
  if (t0 >= e) return;
  int i64 = flags[1];

  for (int b = tid; b < 512; b += 256) lhist[b] = 0;
  __syncthreads();

  if (i64) {
    const long long* dst = (const long long*)ei + e;
    for (int i = t0 + tid; i < tend; i += 256)
      atomicAdd(&lhist[((int)dst[i]) >> BSHIFT], 1);
  } else {
    const int* dst = (const int*)ei + e;
    for (int i = t0 + tid; i < tend; i += 256)
      atomicAdd(&lhist[dst[i] >> BSHIFT], 1);
  }
  __syncthreads();

  for (int b = tid; b < 512; b += 256) {
    int c = lhist[b];
    lbase[b] = c ? atomicAdd(&bucket_cursor[b], c) : 0;
    lhist[b] = 0;  // reuse as rank counter
  }
  __syncthreads();

  if (i64) {
    const long long* srcp = (const long long*)ei;
    const long long* dstp = srcp + e;
    for (int i = t0 + tid; i < tend; i += 256) {
      int s = (int)srcp[i];
      int d = (int)dstp[i];
      int b = d >> BSHIFT;
      int r = atomicAdd(&lhist[b], 1);
      packed[lbase[b] + r] = (s << BSHIFT) | (d & (BNODES - 1));
    }
  } else {
    const int* srcp = (const int*)ei;
    const int* dstp = srcp + e;
    for (int i = t0 + tid; i < tend; i += 256) {
      int s = srcp[i];
      int d = dstp[i];
      int b = d >> BSHIFT;
      int r = atomicAdd(&lhist[b], 1);
      packed[lbase[b] + r] = (s << BSHIFT) | (d & (BNODES - 1));
    }
  }
}

// One block per bucket: LDS counting sort of packed edges -> per-node CSR
// (srcs grouped by dst), row_ptr, dinv. All writes land in the bucket's own
// contiguous csr region (~10 KB) => L2 write-combines, ~1x amplification.
__global__ __launch_bounds__(256) void k_sort_csr(
    const int* __restrict__ packed, const int* __restrict__ bucket_base,
    int* __restrict__ csr, int* __restrict__ row_ptr,
    float* __restrict__ dinv, int n) {
  __shared__ int lcnt[BNODES];
  __shared__ int lofs[BNODES];
  __shared__ int sbuf[BNODES];
  int tid = threadIdx.x;
  int bucket = blockIdx.x;
  int node0 = bucket << BSHIFT;
  int nodes = min(BNODES, n - node0);
  lcnt[tid] = 0;
  __syncthreads();
  int s0 = bucket_base[bucket];
  int s1 = bucket_base[bucket + 1];
  for (int i = s0 + tid; i < s1; i += 256)
    atomicAdd(&lcnt[packed[i] & (BNODES - 1)], 1);
  __syncthreads();
  int v = lcnt[tid];
  sbuf[tid] = v;
  __syncthreads();
  for (int off = 1; off < BNODES; off <<= 1) {
    int tv = (tid >= off) ? sbuf[tid - off] : 0;
    __syncthreads();
    sbuf[tid] += tv;
    __syncthreads();
  }
  int excl = sbuf[tid] - v;
  lofs[tid] = excl;
  lcnt[tid] = 0;  // reuse as rank counter
  if (tid < nodes) {
    row_ptr[node0 + tid] = s0 + excl;
    dinv[node0 + tid] = rsqrtf((float)(v + 1));  // +1 = self loop
  }
  if (node0 + nodes == n && tid == 0) row_ptr[n] = s1;
  __syncthreads();
  for (int i = s0 + tid; i < s1; i += 256) {
    int pk = packed[i];
    int ld = pk & (BNODES - 1);
    int r = atomicAdd(&lcnt[ld], 1);
    csr[s0 + lofs[ld] + r] = pk >> BSHIFT;
  }
}

// ---------------- compute kernels ----------------

// One wave per row (grid-strided). Lane j holds W[:,j] in 64 VGPRs; x-row
// address is wave-uniform (scalar loads). x is bf16 internally; for layer 0
// (x_follow_flag=1) it may be fp32 per flags[0]. hp output bf16.
__global__ __launch_bounds__(256) void k_matmul2(
    const void* __restrict__ x, const void* __restrict__ Wb,
    const void* __restrict__ Wf, const float* __restrict__ dinv,
    unsigned short* __restrict__ outh, const int* __restrict__ flags,
    int nrows, int x_follow_flag) {
  int f32 = flags[0];
  int lane = threadIdx.x & 63;
  int wid = threadIdx.x >> 6;
  float w[D];
  if (f32) {
    const float* W = (const float*)Wf;
#pragma unroll
    for (int k = 0; k < D; k++) w[k] = W[k * D + lane];
  } else {
    const unsigned short* W = (const unsigned short*)Wb;
#pragma unroll
    for (int k = 0; k < D; k++) w[k] = bf16u_to_f32(W[k * D + lane]);
  }
  int xf32 = x_follow_flag && f32;

  int wave = blockIdx.x * 4 + wid;
  int nwaves = gridDim.x * 4;
  for (int row = wave; row < nrows; row += nwaves) {
    int ur = __builtin_amdgcn_readfirstlane(row);
    float acc;
    if (xf32) {
      const float* xr = (const float*)x + (size_t)ur * D;
      float a0 = 0.f, a1 = 0.f, a2 = 0.f, a3 = 0.f;
#pragma unroll
      for (int k = 0; k < D; k += 4) {
        a0 = fmaf(xr[k + 0], w[k + 0], a0);
        a1 = fmaf(xr[k + 1], w[k + 1], a1);
        a2 = fmaf(xr[k + 2], w[k + 2], a2);
        a3 = fmaf(xr[k + 3], w[k + 3], a3);
      }
      acc = (a0 + a1) + (a2 + a3);
    } else {
      const unsigned int* xr =
          (const unsigned int*)((const unsigned short*)x + (size_t)ur * D);
      float a0 = 0.f, a1 = 0.f;
#pragma unroll
      for (int k2 = 0; k2 < D / 2; k2++) {
        unsigned int pk = xr[k2];
        a0 = fmaf(bf16u_to_f32((unsigned short)(pk & 0xffff)), w[2 * k2], a0);
        a1 = fmaf(bf16u_to_f32((unsigned short)(pk >> 16)), w[2 * k2 + 1], a1);
      }
      acc = a0 + a1;
    }
    outh[(size_t)ur * D + lane] = f32_to_bf16u(dinv[ur] * acc);
  }
}

// Final projection: out = x@W + b; x is bf16 internal; store dtype per flag.
__global__ __launch_bounds__(256) void k_matmul_final(
    const unsigned short* __restrict__ x, const void* __restrict__ W,
    const void* __restrict__ bias, void* __restrict__ out,
    const int* __restrict__ flags, int nrows) {
  int f32 = flags[0];
  int lane = threadIdx.x & 63;
  int wid = threadIdx.x >> 6;
  float w[D];
  float b;
  if (f32) {
    const float* Wf = (const float*)W;
#pragma unroll
    for (int k = 0; k < D; k++) w[k] = Wf[k * D + lane];
    b = ((const float*)bias)[lane];
  } else {
    const unsigned short* Wb = (const unsigned short*)W;
#pragma unroll
    for (int k = 0; k < D; k++) w[k] = bf16u_to_f32(Wb[k * D + lane]);
    b = bf16u_to_f32(((const unsigned short*)bias)[lane]);
  }

  int wave = blockIdx.x * 4 + wid;
  int nwaves = gridDim.x * 4;
  for (int row = wave; row < nrows; row += nwaves) {
    int ur = __builtin_amdgcn_readfirstlane(row);
    const unsigned int* xr = (const unsigned int*)(x + (size_t)ur * D);
    float a0 = 0.f, a1 = 0.f;
#pragma unroll
    for (int k2 = 0; k2 < D / 2; k2++) {
      unsigned int pk = xr[k2];
      a0 = fmaf(bf16u_to_f32((unsigned short)(pk & 0xffff)), w[2 * k2], a0);
      a1 = fmaf(bf16u_to_f32((unsigned short)(pk >> 16)), w[2 * k2 + 1], a1);
    }
    float r = a0 + a1 + b;
    size_t idx = (size_t)ur * D + lane;
    if (f32)
      ((float*)out)[idx] = r;
    else
      ((unsigned short*)out)[idx] = f32_to_bf16u(r);
  }
}

// One wave per node. Quarter-split: 16 lanes x ushort4 = one 128B bf16 row;
// 4 edges per load instruction, unroll 4 => 16 gathers in flight per wave.
// Merge quarters with 2x shfl_xor; x' = relu(dinv*(self+sum)+bias), bf16 out.
__global__ __launch_bounds__(256) void k_agg4(
    const unsigned short* __restrict__ hp, const int* __restrict__ row_ptr,
    const int* __restrict__ csr, const float* __restrict__ dinv,
    const void* __restrict__ bias_b, const void* __restrict__ bias_f,
    const int* __restrict__ flags, unsigned short* __restrict__ xout, int n) {
  int lane = threadIdx.x & 63;
  int q = lane >> 4;   // quarter 0..3
  int f = lane & 15;   // ushort4 slot (features 4f..4f+3)
  int wid = threadIdx.x >> 6;
  int node = blockIdx.x * 4 + wid;
  if (node >= n) return;
  int un = __builtin_amdgcn_readfirstlane(node);

  int s0 = row_ptr[un];
  int s1 = row_ptr[un + 1];
  const ushort4* hp4 = (const ushort4*)hp;  // row stride = 16 ushort4

  float a0 = 0.f, a1 = 0.f, a2 = 0.f, a3 = 0.f;
  for (int base = s0; base < s1; base += 16) {
    int idx[4];
    bool m[4];
#pragma unroll
    for (int u = 0; u < 4; u++) {
      int i = base + 4 * u + q;
      m[u] = i < s1;
      idx[u] = m[u] ? i : s0;  // s0 valid: loop entered => s1 > s0
    }
    int srcs[4];
#pragma unroll
    for (int u = 0; u < 4; u++) srcs[u] = csr[idx[u]];
    ushort4 v[4];
#pragma unroll
    for (int u = 0; u < 4; u++) v[u] = hp4[(size_t)srcs[u] * 16 + f];
#pragma unroll
    for (int u = 0; u < 4; u++) {
      if (m[u]) {
        a0 += bf16u_to_f32(v[u].x);
        a1 += bf16u_to_f32(v[u].y);
        a2 += bf16u_to_f32(v[u].z);
        a3 += bf16u_to_f32(v[u].w);
      }
    }
  }
  // merge the 4 quarters (lanes l, l^16, l^32, l^48 share feature slot f)
  a0 += __shfl_xor(a0, 16, 64); a0 += __shfl_xor(a0, 32, 64);
  a1 += __shfl_xor(a1, 16, 64); a1 += __shfl_xor(a1, 32, 64);
  a2 += __shfl_xor(a2, 16, 64); a2 += __shfl_xor(a2, 32, 64);
  a3 += __shfl_xor(a3, 16, 64); a3 += __shfl_xor(a3, 32, 64);

  if (q == 0) {
    int f32 = flags[0];
    ushort4 sv = hp4[(size_t)un * 16 + f];  // self loop
    a0 += bf16u_to_f32(sv.x);
    a1 += bf16u_to_f32(sv.y);
    a2 += bf16u_to_f32(sv.z);
    a3 += bf16u_to_f32(sv.w);
    float b0, b1, b2, b3;
    if (f32) {
      const float4 bv = ((const float4*)bias_f)[f];
      b0 = bv.x; b1 = bv.y; b2 = bv.z; b3 = bv.w;
    } else {
      ushort4 bv = ((const ushort4*)bias_b)[f];
      b0 = bf16u_to_f32(bv.x); b1 = bf16u_to_f32(bv.y);
      b2 = bf16u_to_f32(bv.z); b3 = bf16u_to_f32(bv.w);
    }
    float dv = dinv[un];
    ushort4 o;
    o.x = f32_to_bf16u(fmaxf(fmaf(dv, a0, b0), 0.f));
    o.y = f32_to_bf16u(fmaxf(fmaf(dv, a1, b1), 0.f));
    o.z = f32_to_bf16u(fmaxf(fmaf(dv, a2, b2), 0.f));
    o.w = f32_to_bf16u(fmaxf(fmaf(dv, a3, b3), 0.f));
    ((ushort4*)xout)[(size_t)un * 16 + f] = o;
  }
}

// ---------------- launch ----------------

extern "C" void kernel_launch(void* const* d_in, const int* in_sizes, int n_in,
                              void* d_out, int out_size, void* d_ws,
                              size_t ws_size, hipStream_t stream) {
  const void* x0 = d_in[0];
  const void* ei = d_in[1];
  const char* Ws = (const char*)d_in[2];
  const char* bs = (const char*)d_in[3];
  const void* Wout = d_in[4];
  const void* bout = d_in[5];

  const int N = in_sizes[0] / D;  // 100000
  const int E = in_sizes[1] / 2;  // 1000000
  const int NBUC = (N + BNODES - 1) >> BSHIFT;  // 391

  char* p = (char*)d_ws;
  auto alloc = [&](size_t bytes) {
    char* r = p;
    p += (bytes + 511) & ~(size_t)511;
    return r;
  };
  int* flags = (int*)alloc(8);
  int* bucket_cnt = (int*)alloc(512 * 4);
  int* bucket_base = (int*)alloc(513 * 4);
  int* bucket_cursor = (int*)alloc(512 * 4);
  int* packed = (int*)alloc((size_t)E * 4);
  int* csr = (int*)alloc((size_t)E * 4);
  int* row_ptr = (int*)alloc((size_t)(N + 1) * 4);
  float* dinv = (float*)alloc((size_t)N * 4);
  unsigned short* hp = (unsigned short*)alloc((size_t)N * D * 2);
  unsigned short* xbuf = (unsigned short*)alloc((size_t)N * D * 2);
  (void)ws_size;
  (void)n_in;
  (void)out_size;

  hipMemsetAsync(bucket_cnt, 0, 512 * 4, stream);

  k_probe<<<1, 64, 0, stream>>>(Ws, ei, flags);
  k_hist<<<512, 256, 0, stream>>>(ei, flags, bucket_cnt, E);
  k_scan_buckets<<<1, 512, 0, stream>>>(bucket_cnt, bucket_base, bucket_cursor,
                                        NBUC, E);
  int ptiles = (E + PTILE - 1) / PTILE;
  k_partition<<<ptiles, 256, 0, stream>>>(ei, flags, bucket_cursor, packed, E);
  k_sort_csr<<<NBUC, 256, 0, stream>>>(packed, bucket_base, csr, row_ptr, dinv,
                                       N);

  const size_t WSZ = (size_t)D * D;
  for (int l = 0; l < 3; ++l) {
    const void* W_b = Ws + (size_t)l * WSZ * 2;  // byte offset if bf16
    const void* W_f = Ws + (size_t)l * WSZ * 4;  // byte offset if fp32
    const void* b_b = bs + (size_t)l * D * 2;
    const void* b_f = bs + (size_t)l * D * 4;
    const void* xin = (l == 0) ? x0 : (const void*)xbuf;
    k_matmul2<<<1024, 256, 0, stream>>>(xin, W_b, W_f, dinv, hp, flags, N,
                                        (l == 0) ? 1 : 0);
    k_agg4<<<(N + 3) / 4, 256, 0, stream>>>(hp, row_ptr, csr, dinv, b_b, b_f,
                                            flags, xbuf, N);
  }
  k_matmul_final<<<1024, 256, 0, stream>>>(xbuf, Wout, bout, d_out, flags, N);
}

// Round 6
// 329.708 us; speedup vs baseline: 4.9272x; 1.3120x over previous
//
#include <hip/hip_runtime.h>
#include <hip/hip_bf16.h>

#define D 64
#define BSHIFT 8           // 256 nodes per bucket
#define BNODES 256
#define PTILE 8192         // edges per partition tile

typedef __attribute__((ext_vector_type(8))) short short8;
typedef __attribute__((ext_vector_type(4))) float float4v;

// flags[0] = 1 if float tensors are fp32 (else bf16)
// flags[1] = 1 if edge_index is int64 (else int32)

__device__ __forceinline__ float bf16u_to_f32(unsigned short u) {
  union { unsigned int i; float f; } c;
  c.i = ((unsigned int)u) << 16;
  return c.f;
}

__device__ __forceinline__ unsigned short f32_to_bf16u(float f) {
  union { float f; unsigned int u; } c;
  c.f = f;
  unsigned int r = (c.u + 0x7fffu + ((c.u >> 16) & 1u)) >> 16;  // RNE
  return (unsigned short)r;
}

__global__ void k_probe(const void* W, const void* ei, int* flags) {
  int lane = threadIdx.x & 63;
  const unsigned short* wb = (const unsigned short*)W;
  bool big = false;
  for (int i = lane; i < 512; i += 64) {
    float v = bf16u_to_f32(wb[i]);
    if (!(fabsf(v) < 100.f)) big = true;  // NaN lands here too
  }
  int anybig = __any(big);
  const int* e32 = (const int*)ei;
  bool nz = (e32[2 * lane + 1] != 0);  // odd slots of first 64 pairs
  int anynz = __any(nz);
  if (threadIdx.x == 0) {
    flags[0] = anybig ? 1 : 0;  // huge magnitudes => data is actually fp32
    flags[1] = anynz ? 0 : 1;   // all-zero odd slots => int64
  }
}

// ---------------- bucketed graph build ----------------

__global__ __launch_bounds__(256) void k_hist(const void* __restrict__ ei,
                                              const int* __restrict__ flags,
                                              int* __restrict__ bucket_cnt,
                                              int e) {
  __shared__ int h[512];
  for (int b = threadIdx.x; b < 512; b += 256) h[b] = 0;
  __syncthreads();
  int i64 = flags[1];
  int i = blockIdx.x * 256 + threadIdx.x;
  int stride = gridDim.x * 256;
  if (i64) {
    const long long* dst = (const long long*)ei + e;
    for (; i < e; i += stride) atomicAdd(&h[((int)dst[i]) >> BSHIFT], 1);
  } else {
    const int* dst = (const int*)ei + e;
    for (; i < e; i += stride) atomicAdd(&h[dst[i] >> BSHIFT], 1);
  }
  __syncthreads();
  for (int b = threadIdx.x; b < 512; b += 256)
    if (h[b]) atomicAdd(&bucket_cnt[b], h[b]);
}

__global__ __launch_bounds__(512) void k_scan_buckets(
    const int* __restrict__ bucket_cnt, int* __restrict__ bucket_base,
    int* __restrict__ bucket_cursor, int nbuc, int e) {
  __shared__ int lds[512];
  int t = threadIdx.x;
  int v = (t < nbuc) ? bucket_cnt[t] : 0;
  lds[t] = v;
  __syncthreads();
  for (int off = 1; off < 512; off <<= 1) {
    int tv = (t >= off) ? lds[t - off] : 0;
    __syncthreads();
    lds[t] += tv;
    __syncthreads();
  }
  int base = lds[t] - v;  // exclusive
  if (t < nbuc) {
    bucket_base[t] = base;
    bucket_cursor[t] = base;
  }
  if (t == 0) bucket_base[nbuc] = e;
}

// LDS-staged partition: per tile, histogram -> one global atomic per
// (tile,bucket) reserving a contiguous run -> rank -> packed (src<<8)|ldst.
__global__ __launch_bounds__(256) void k_partition(
    const void* __restrict__ ei, const int* __restrict__ flags,
    int* __restrict__ bucket_cursor, int* __restrict__ packed, int e) {
  __shared__ int lhist[512];
  __shared__ int lbase[512];
  int tid = threadIdx.x;
  int t0 = blockIdx.x * PTILE;
  int tend = min(t0 + PTILE, e);
  if (t0 >= e) return;
  int i64 = flags[1];

  for (int b = tid; b < 512; b += 256) lhist[b] = 0;
  __syncthreads();

  if (i64) {
    const long long* dst = (const long long*)ei + e;
    for (int i = t0 + tid; i < tend; i += 256)
      atomicAdd(&lhist[((int)dst[i]) >> BSHIFT], 1);
  } else {
    const int* dst = (const int*)ei + e;
    for (int i = t0 + tid; i < tend; i += 256)
      atomicAdd(&lhist[dst[i] >> BSHIFT], 1);
  }
  __syncthreads();

  for (int b = tid; b < 512; b += 256) {
    int c = lhist[b];
    lbase[b] = c ? atomicAdd(&bucket_cursor[b], c) : 0;
    lhist[b] = 0;  // reuse as rank counter
  }
  __syncthreads();

  if (i64) {
    const long long* srcp = (const long long*)ei;
    const long long* dstp = srcp + e;
    for (int i = t0 + tid; i < tend; i += 256) {
      int s = (int)srcp[i];
      int d = (int)dstp[i];
      int b = d >> BSHIFT;
      int r = atomicAdd(&lhist[b], 1);
      packed[lbase[b] + r] = (s << BSHIFT) | (d & (BNODES - 1));
    }
  } else {
    const int* srcp = (const int*)ei;
    const int* dstp = srcp + e;
    for (int i = t0 + tid; i < tend; i += 256) {
      int s = srcp[i];
      int d = dstp[i];
      int b = d >> BSHIFT;
      int r = atomicAdd(&lhist[b], 1);
      packed[lbase[b] + r] = (s << BSHIFT) | (d & (BNODES - 1));
    }
  }
}

// One block per bucket: LDS counting sort -> per-node CSR, row_ptr, dinv.
__global__ __launch_bounds__(256) void k_sort_csr(
    const int* __restrict__ packed, const int* __restrict__ bucket_base,
    int* __restrict__ csr, int* __restrict__ row_ptr,
    float* __restrict__ dinv, int n) {
  __shared__ int lcnt[BNODES];
  __shared__ int lofs[BNODES];
  __shared__ int sbuf[BNODES];
  int tid = threadIdx.x;
  int bucket = blockIdx.x;
  int node0 = bucket << BSHIFT;
  int nodes = min(BNODES, n - node0);
  lcnt[tid] = 0;
  __syncthreads();
  int s0 = bucket_base[bucket];
  int s1 = bucket_base[bucket + 1];
  for (int i = s0 + tid; i < s1; i += 256)
    atomicAdd(&lcnt[packed[i] & (BNODES - 1)], 1);
  __syncthreads();
  int v = lcnt[tid];
  sbuf[tid] = v;
  __syncthreads();
  for (int off = 1; off < BNODES; off <<= 1) {
    int tv = (tid >= off) ? sbuf[tid - off] : 0;
    __syncthreads();
    sbuf[tid] += tv;
    __syncthreads();
  }
  int excl = sbuf[tid] - v;
  lofs[tid] = excl;
  lcnt[tid] = 0;  // reuse as rank counter
  if (tid < nodes) {
    row_ptr[node0 + tid] = s0 + excl;
    dinv[node0 + tid] = rsqrtf((float)(v + 1));  // +1 = self loop
  }
  if (node0 + nodes == n && tid == 0) row_ptr[n] = s1;
  __syncthreads();
  for (int i = s0 + tid; i < s1; i += 256) {
    int pk = packed[i];
    int ld = pk & (BNODES - 1);
    int r = atomicAdd(&lcnt[ld], 1);
    csr[s0 + lofs[ld] + r] = pk >> BSHIFT;
  }
}

// ---------------- weight prep + x0 convert ----------------

// Transpose the 4 weight matrices into WT[l][n][k] (bf16) and convert the 4
// bias vectors to fp32. Ws holds 3, Wout 1; bs holds 3, bout 1.
__global__ __launch_bounds__(256) void k_prep(
    const void* __restrict__ Ws, const void* __restrict__ Wout,
    const void* __restrict__ bs, const void* __restrict__ bout,
    const int* __restrict__ flags, unsigned short* __restrict__ WT,
    float* __restrict__ biasf) {
  int f32 = flags[0];
  int tid = threadIdx.x;
  // 4 matrices x 4096 elements
  for (int i = tid; i < 4 * 4096; i += 256) {
    int l = i >> 12;
    int r = i & 4095;
    int k = r >> 6;
    int nn = r & 63;
    unsigned short v;
    if (l < 3) {
      v = f32 ? f32_to_bf16u(((const float*)Ws)[l * 4096 + r])
              : ((const unsigned short*)Ws)[l * 4096 + r];
    } else {
      v = f32 ? f32_to_bf16u(((const float*)Wout)[r])
              : ((const unsigned short*)Wout)[r];
    }
    WT[l * 4096 + nn * 64 + k] = v;  // transposed
  }
  for (int i = tid; i < 4 * 64; i += 256) {
    int l = i >> 6;
    int j = i & 63;
    float v;
    if (l < 3)
      v = f32 ? ((const float*)bs)[l * 64 + j]
              : bf16u_to_f32(((const unsigned short*)bs)[l * 64 + j]);
    else
      v = f32 ? ((const float*)bout)[j]
              : bf16u_to_f32(((const unsigned short*)bout)[j]);
    biasf[i] = v;
  }
}

__global__ __launch_bounds__(256) void k_load_x(
    const void* __restrict__ in, const int* __restrict__ flags,
    unsigned short* __restrict__ out, int n) {
  int f32 = flags[0];
  int i = blockIdx.x * blockDim.x + threadIdx.x;
  int stride = gridDim.x * blockDim.x;
  if (f32) {
    const float* p = (const float*)in;
    for (; i < n; i += stride) out[i] = f32_to_bf16u(p[i]);
  } else {
    const unsigned short* p = (const unsigned short*)in;
    for (; i < n; i += stride) out[i] = p[i];
  }
}

// ---------------- MFMA GEMM ----------------
// hp[N,64] = scale_row ⊙ (x[N,64] @ W[64,64])  (mode 0, bf16 out)
// out[N,64] = x @ W + bias                     (mode 1, dtype per flag)
// A-frag: A[m=lane&15][k=(lane>>4)*8+j]; B from WT[n][k] (same index shape);
// C/D: col=lane&15, row=(lane>>4)*4+reg  [per cdna_hip_programming §3].
__global__ __launch_bounds__(256) void k_gemm(
    const unsigned short* __restrict__ xin,
    const unsigned short* __restrict__ WT, const float* __restrict__ dinv,
    const float* __restrict__ bias, void* __restrict__ out,
    const int* __restrict__ flags, int ntiles, int mode) {
  int lane = threadIdx.x & 63;
  int wid = threadIdx.x >> 6;
  int f = lane & 15;  // col n (C) / row m (A)
  int q = lane >> 4;  // quarter

  short8 bfr[4][2];
#pragma unroll
  for (int ct = 0; ct < 4; ct++)
#pragma unroll
    for (int kt = 0; kt < 2; kt++)
      bfr[ct][kt] =
          *(const short8*)(WT + (size_t)(f + 16 * ct) * 64 + kt * 32 + q * 8);

  int wave = blockIdx.x * 4 + wid;
  int nwaves = gridDim.x * 4;
  for (int t = wave; t < ntiles; t += nwaves) {
    int row0 = t * 16;
    const unsigned short* xr = xin + (size_t)(row0 + f) * 64 + q * 8;
    short8 a0 = *(const short8*)(xr);
    short8 a1 = *(const short8*)(xr + 32);
    float4v acc[4];
#pragma unroll
    for (int ct = 0; ct < 4; ct++) {
      float4v z = {0.f, 0.f, 0.f, 0.f};
      acc[ct] =
          __builtin_amdgcn_mfma_f32_16x16x32_bf16(a0, bfr[ct][0], z, 0, 0, 0);
      acc[ct] = __builtin_amdgcn_mfma_f32_16x16x32_bf16(a1, bfr[ct][1],
                                                        acc[ct], 0, 0, 0);
    }
    if (mode == 0) {
      float4 dv = *(const float4*)(dinv + row0 + q * 4);
      float d[4] = {dv.x, dv.y, dv.z, dv.w};
      unsigned short* op = (unsigned short*)out;
#pragma unroll
      for (int reg = 0; reg < 4; reg++) {
        size_t rb = (size_t)(row0 + q * 4 + reg) * 64 + f;
#pragma unroll
        for (int ct = 0; ct < 4; ct++)
          op[rb + 16 * ct] = f32_to_bf16u(d[reg] * acc[ct][reg]);
      }
    } else {
      int f32o = flags[0];
      float bv[4];
#pragma unroll
      for (int ct = 0; ct < 4; ct++) bv[ct] = bias[f + 16 * ct];
      if (f32o) {
        float* op = (float*)out;
#pragma unroll
        for (int reg = 0; reg < 4; reg++) {
          size_t rb = (size_t)(row0 + q * 4 + reg) * 64 + f;
#pragma unroll
          for (int ct = 0; ct < 4; ct++)
            op[rb + 16 * ct] = acc[ct][reg] + bv[ct];
        }
      } else {
        unsigned short* op = (unsigned short*)out;
#pragma unroll
        for (int reg = 0; reg < 4; reg++) {
          size_t rb = (size_t)(row0 + q * 4 + reg) * 64 + f;
#pragma unroll
          for (int ct = 0; ct < 4; ct++)
            op[rb + 16 * ct] = f32_to_bf16u(acc[ct][reg] + bv[ct]);
        }
      }
    }
  }
}

// ---------------- aggregation ----------------
// One wave per node. Quarter-split: 16 lanes x ushort4 = one 128B bf16 row;
// 4 edges per load instruction, unroll 4 => 16 gathers in flight per wave.
__global__ __launch_bounds__(256) void k_agg4(
    const unsigned short* __restrict__ hp, const int* __restrict__ row_ptr,
    const int* __restrict__ csr, const float* __restrict__ dinv,
    const float* __restrict__ biasf, unsigned short* __restrict__ xout,
    int n) {
  int lane = threadIdx.x & 63;
  int q = lane >> 4;  // quarter 0..3
  int f = lane & 15;  // ushort4 slot (features 4f..4f+3)
  int wid = threadIdx.x >> 6;
  int node = blockIdx.x * 4 + wid;
  if (node >= n) return;
  int un = __builtin_amdgcn_readfirstlane(node);

  int s0 = row_ptr[un];
  int s1 = row_ptr[un + 1];
  const ushort4* hp4 = (const ushort4*)hp;  // row stride = 16 ushort4

  float a0 = 0.f, a1 = 0.f, a2 = 0.f, a3 = 0.f;
  for (int base = s0; base < s1; base += 16) {
    int idx[4];
    bool m[4];
#pragma unroll
    for (int u = 0; u < 4; u++) {
      int i = base + 4 * u + q;
      m[u] = i < s1;
      idx[u] = m[u] ? i : s0;  // s0 valid: loop entered => s1 > s0
    }
    int srcs[4];
#pragma unroll
    for (int u = 0; u < 4; u++) srcs[u] = csr[idx[u]];
    ushort4 v[4];
#pragma unroll
    for (int u = 0; u < 4; u++) v[u] = hp4[(size_t)srcs[u] * 16 + f];
#pragma unroll
    for (int u = 0; u < 4; u++) {
      if (m[u]) {
        a0 += bf16u_to_f32(v[u].x);
        a1 += bf16u_to_f32(v[u].y);
        a2 += bf16u_to_f32(v[u].z);
        a3 += bf16u_to_f32(v[u].w);
      }
    }
  }
  a0 += __shfl_xor(a0, 16, 64); a0 += __shfl_xor(a0, 32, 64);
  a1 += __shfl_xor(a1, 16, 64); a1 += __shfl_xor(a1, 32, 64);
  a2 += __shfl_xor(a2, 16, 64); a2 += __shfl_xor(a2, 32, 64);
  a3 += __shfl_xor(a3, 16, 64); a3 += __shfl_xor(a3, 32, 64);

  if (q == 0) {
    ushort4 sv = hp4[(size_t)un * 16 + f];  // self loop
    a0 += bf16u_to_f32(sv.x);
    a1 += bf16u_to_f32(sv.y);
    a2 += bf16u_to_f32(sv.z);
    a3 += bf16u_to_f32(sv.w);
    float4 bv = ((const float4*)biasf)[f];
    float dv = dinv[un];
    ushort4 o;
    o.x = f32_to_bf16u(fmaxf(fmaf(dv, a0, bv.x), 0.f));
    o.y = f32_to_bf16u(fmaxf(fmaf(dv, a1, bv.y), 0.f));
    o.z = f32_to_bf16u(fmaxf(fmaf(dv, a2, bv.z), 0.f));
    o.w = f32_to_bf16u(fmaxf(fmaf(dv, a3, bv.w), 0.f));
    ((ushort4*)xout)[(size_t)un * 16 + f] = o;
  }
}

// ---------------- launch ----------------

extern "C" void kernel_launch(void* const* d_in, const int* in_sizes, int n_in,
                              void* d_out, int out_size, void* d_ws,
                              size_t ws_size, hipStream_t stream) {
  const void* x0 = d_in[0];
  const void* ei = d_in[1];
  const void* Ws = d_in[2];
  const void* bs = d_in[3];
  const void* Wout = d_in[4];
  const void* bout = d_in[5];

  const int N = in_sizes[0] / D;  // 100000
  const int E = in_sizes[1] / 2;  // 1000000
  const int NBUC = (N + BNODES - 1) >> BSHIFT;  // 391
  const int NT = N / 16;  // 6250 row tiles (N divisible by 16)

  char* p = (char*)d_ws;
  auto alloc = [&](size_t bytes) {
    char* r = p;
    p += (bytes + 511) & ~(size_t)511;
    return r;
  };
  int* flags = (int*)alloc(8);
  int* bucket_cnt = (int*)alloc(512 * 4);
  int* bucket_base = (int*)alloc(513 * 4);
  int* bucket_cursor = (int*)alloc(512 * 4);
  int* packed = (int*)alloc((size_t)E * 4);
  int* csr = (int*)alloc((size_t)E * 4);
  int* row_ptr = (int*)alloc((size_t)(N + 1) * 4);
  float* dinv = (float*)alloc((size_t)N * 4);
  unsigned short* WT = (unsigned short*)alloc(4 * 4096 * 2);
  float* biasf = (float*)alloc(4 * 64 * 4);
  unsigned short* hp = (unsigned short*)alloc((size_t)N * D * 2);
  unsigned short* xa = (unsigned short*)alloc((size_t)N * D * 2);
  unsigned short* xb = (unsigned short*)alloc((size_t)N * D * 2);
  (void)ws_size;
  (void)n_in;
  (void)out_size;

  hipMemsetAsync(bucket_cnt, 0, 512 * 4, stream);

  k_probe<<<1, 64, 0, stream>>>(Ws, ei, flags);
  k_hist<<<512, 256, 0, stream>>>(ei, flags, bucket_cnt, E);
  k_scan_buckets<<<1, 512, 0, stream>>>(bucket_cnt, bucket_base, bucket_cursor,
                                        NBUC, E);
  int ptiles = (E + PTILE - 1) / PTILE;
  k_partition<<<ptiles, 256, 0, stream>>>(ei, flags, bucket_cursor, packed, E);
  k_sort_csr<<<NBUC, 256, 0, stream>>>(packed, bucket_base, csr, row_ptr, dinv,
                                       N);
  k_prep<<<1, 256, 0, stream>>>(Ws, Wout, bs, bout, flags, WT, biasf);
  k_load_x<<<2048, 256, 0, stream>>>(x0, flags, xa, N * D);

  for (int l = 0; l < 3; ++l) {
    const unsigned short* xin = (l == 0) ? xa : xb;
    k_gemm<<<784, 256, 0, stream>>>(xin, WT + l * 4096, dinv, nullptr, hp,
                                    flags, NT, 0);
    k_agg4<<<(N + 3) / 4, 256, 0, stream>>>(hp, row_ptr, csr, dinv,
                                            biasf + l * 64, xb, N);
  }
  k_gemm<<<784, 256, 0, stream>>>(xb, WT + 3 * 4096, nullptr, biasf + 3 * 64,
                                  d_out, flags, NT, 1);
}

// Round 7
// 301.629 us; speedup vs baseline: 5.3859x; 1.0931x over previous
//
#include <hip/hip_runtime.h>
#include <hip/hip_bf16.h>

#define D 64
#define BSHIFT 8           // 256 nodes per bucket
#define BNODES 256
#define BCAP 4096          // edge capacity per bucket region (exp 2558, +30 sigma)
#define PTILE 8192         // edges per partition tile

typedef __attribute__((ext_vector_type(8))) short short8;
typedef __attribute__((ext_vector_type(4))) float float4v;

// flags[0] = 1 if float tensors are fp32 (else bf16)
// flags[1] = 1 if edge_index is int64 (else int32)

__device__ __forceinline__ float bf16u_to_f32(unsigned short u) {
  union { unsigned int i; float f; } c;
  c.i = ((unsigned int)u) << 16;
  return c.f;
}

__device__ __forceinline__ unsigned short f32_to_bf16u(float f) {
  union { float f; unsigned int u; } c;
  c.f = f;
  unsigned int r = (c.u + 0x7fffu + ((c.u >> 16) & 1u)) >> 16;  // RNE
  return (unsigned short)r;
}

// ---------------- setup: probe dtypes + weight prep + cursor init ----------------

__global__ __launch_bounds__(512) void k_setup(
    const void* __restrict__ Ws, const void* __restrict__ Wout,
    const void* __restrict__ bs, const void* __restrict__ bout,
    const void* __restrict__ ei, int* __restrict__ flags,
    unsigned short* __restrict__ WT, float* __restrict__ biasf,
    int* __restrict__ bucket_cursor) {
  __shared__ int lf[2];
  int tid = threadIdx.x;
  if (tid < 64) {
    const unsigned short* wb = (const unsigned short*)Ws;
    bool big = false;
    for (int i = tid; i < 512; i += 64) {
      float v = bf16u_to_f32(wb[i]);
      if (!(fabsf(v) < 100.f)) big = true;  // NaN lands here too
    }
    int anybig = __any(big);
    const int* e32 = (const int*)ei;
    bool nz = (e32[2 * tid + 1] != 0);  // odd words of first 64 pairs
    int anynz = __any(nz);
    if (tid == 0) {
      lf[0] = anybig ? 1 : 0;  // huge magnitudes => data is actually fp32
      lf[1] = anynz ? 0 : 1;   // all-zero odd words => int64
      flags[0] = lf[0];
      flags[1] = lf[1];
    }
  }
  __syncthreads();
  int f32 = lf[0];

  bucket_cursor[tid] = tid * BCAP;  // 512 regions (391 used)

  // transpose 4 weight matrices into WT[l][n][k] (bf16)
  for (int i = tid; i < 4 * 4096; i += 512) {
    int l = i >> 12;
    int r = i & 4095;
    int k = r >> 6;
    int nn = r & 63;
    unsigned short v;
    if (l < 3) {
      v = f32 ? f32_to_bf16u(((const float*)Ws)[l * 4096 + r])
              : ((const unsigned short*)Ws)[l * 4096 + r];
    } else {
      v = f32 ? f32_to_bf16u(((const float*)Wout)[r])
              : ((const unsigned short*)Wout)[r];
    }
    WT[l * 4096 + nn * 64 + k] = v;
  }
  // biases -> fp32
  for (int i = tid; i < 4 * 64; i += 512) {
    int l = i >> 6;
    int j = i & 63;
    float v;
    if (l < 3)
      v = f32 ? ((const float*)bs)[l * 64 + j]
              : bf16u_to_f32(((const unsigned short*)bs)[l * 64 + j]);
    else
      v = f32 ? ((const float*)bout)[j]
              : bf16u_to_f32(((const unsigned short*)bout)[j]);
    biasf[i] = v;
  }
}

// ---------------- bucketed partition (fixed-capacity regions) ----------------

// LDS-staged partition: per tile, histogram -> one global atomic per
// (tile,bucket) reserving a contiguous run in the bucket's region -> rank ->
// write packed (src<<8)|localdst. ~1.3x write amplification.
__global__ __launch_bounds__(256) void k_partition(
    const void* __restrict__ ei, const int* __restrict__ flags,
    int* __restrict__ bucket_cursor, int* __restrict__ packed, int e) {
  __shared__ int lhist[512];
  __shared__ int lbase[512];
  int tid = threadIdx.x;
  int t0 = blockIdx.x * PTILE;
  int tend = min(t0 + PTILE, e);
  if (t0 >= e) return;
  int i64 = flags[1];

  for (int b = tid; b < 512; b += 256) lhist[b] = 0;
  __syncthreads();

  if (i64) {
    const long long* dst = (const long long*)ei + e;
    for (int i = t0 + tid; i < tend; i += 256)
      atomicAdd(&lhist[((int)dst[i]) >> BSHIFT], 1);
  } else {
    const int* dst = (const int*)ei + e;
    for (int i = t0 + tid; i < tend; i += 256)
      atomicAdd(&lhist[dst[i] >> BSHIFT], 1);
  }
  __syncthreads();

  for (int b = tid; b < 512; b += 256) {
    int c = lhist[b];
    lbase[b] = c ? atomicAdd(&bucket_cursor[b], c) : 0;
    lhist[b] = 0;  // reuse as rank counter
  }
  __syncthreads();

  if (i64) {
    const long long* srcp = (const long long*)ei;
    const long long* dstp = srcp + e;
    for (int i = t0 + tid; i < tend; i += 256) {
      int s = (int)srcp[i];
      int d = (int)dstp[i];
      int b = d >> BSHIFT;
      int r = atomicAdd(&lhist[b], 1);
      packed[lbase[b] + r] = (s << BSHIFT) | (d & (BNODES - 1));
    }
  } else {
    const int* srcp = (const int*)ei;
    const int* dstp = srcp + e;
    for (int i = t0 + tid; i < tend; i += 256) {
      int s = srcp[i];
      int d = dstp[i];
      int b = d >> BSHIFT;
      int r = atomicAdd(&lhist[b], 1);
      packed[lbase[b] + r] = (s << BSHIFT) | (d & (BNODES - 1));
    }
  }
}

// One block per bucket: LDS counting sort -> per-node src list (grouped by
// dst) in the bucket's csr region, rowrange (beg,end), dinv.
__global__ __launch_bounds__(256) void k_sort_csr(
    const int* __restrict__ packed, const int* __restrict__ bucket_cursor,
    int* __restrict__ csr, int2* __restrict__ rowrange,
    float* __restrict__ dinv, int n) {
  __shared__ int lcnt[BNODES];
  __shared__ int lofs[BNODES];
  __shared__ int sbuf[BNODES];
  int tid = threadIdx.x;
  int bucket = blockIdx.x;
  int node0 = bucket << BSHIFT;
  int nodes = min(BNODES, n - node0);
  int s0 = bucket * BCAP;
  int s1 = bucket_cursor[bucket];  // region end after partition
  lcnt[tid] = 0;
  __syncthreads();
  for (int i = s0 + tid; i < s1; i += 256)
    atomicAdd(&lcnt[packed[i] & (BNODES - 1)], 1);
  __syncthreads();
  int v = lcnt[tid];
  sbuf[tid] = v;
  __syncthreads();
  for (int off = 1; off < BNODES; off <<= 1) {
    int tv = (tid >= off) ? sbuf[tid - off] : 0;
    __syncthreads();
    sbuf[tid] += tv;
    __syncthreads();
  }
  int excl = sbuf[tid] - v;
  lofs[tid] = excl;
  lcnt[tid] = 0;  // reuse as rank counter
  if (tid < nodes) {
    rowrange[node0 + tid] = make_int2(s0 + excl, s0 + excl + v);
    dinv[node0 + tid] = rsqrtf((float)(v + 1));  // +1 = self loop
  }
  __syncthreads();
  for (int i = s0 + tid; i < s1; i += 256) {
    int pk = packed[i];
    int ld = pk & (BNODES - 1);
    int r = atomicAdd(&lcnt[ld], 1);
    csr[s0 + lofs[ld] + r] = pk >> BSHIFT;
  }
}

// ---------------- MFMA GEMM ----------------
// mode 0: hp[N,64] = dinv_row ⊙ (x @ W), bf16 out
// mode 1: out[N,64] = x @ W + bias, dtype per flags[0]
// xin_is_input: x may be fp32 per flags[0] (layer-0 reads d_in[0] directly)
// A-frag: A[m=lane&15][k=q*8+j]; B from WT[n][k];
// C/D: col=lane&15, row=q*4+reg  [cdna_hip_programming §3, m89-verified].
__global__ __launch_bounds__(256) void k_gemm(
    const void* __restrict__ xin, const unsigned short* __restrict__ WT,
    const float* __restrict__ dinv, const float* __restrict__ bias,
    void* __restrict__ out, const int* __restrict__ flags, int ntiles,
    int mode, int xin_is_input) {
  int lane = threadIdx.x & 63;
  int wid = threadIdx.x >> 6;
  int f = lane & 15;  // col n (C) / row m (A)
  int q = lane >> 4;  // quarter
  int xf32 = xin_is_input ? flags[0] : 0;

  short8 bfr[4][2];
#pragma unroll
  for (int ct = 0; ct < 4; ct++)
#pragma unroll
    for (int kt = 0; kt < 2; kt++)
      bfr[ct][kt] =
          *(const short8*)(WT + (size_t)(f + 16 * ct) * 64 + kt * 32 + q * 8);

  int wave = blockIdx.x * 4 + wid;
  int nwaves = gridDim.x * 4;
  for (int t = wave; t < ntiles; t += nwaves) {
    int row0 = t * 16;
    short8 a0, a1;
    if (xf32) {
      const float* xr = (const float*)xin + (size_t)(row0 + f) * 64 + q * 8;
      float4 u0 = *(const float4*)(xr);
      float4 u1 = *(const float4*)(xr + 4);
      float4 u2 = *(const float4*)(xr + 32);
      float4 u3 = *(const float4*)(xr + 36);
      a0[0] = (short)f32_to_bf16u(u0.x); a0[1] = (short)f32_to_bf16u(u0.y);
      a0[2] = (short)f32_to_bf16u(u0.z); a0[3] = (short)f32_to_bf16u(u0.w);
      a0[4] = (short)f32_to_bf16u(u1.x); a0[5] = (short)f32_to_bf16u(u1.y);
      a0[6] = (short)f32_to_bf16u(u1.z); a0[7] = (short)f32_to_bf16u(u1.w);
      a1[0] = (short)f32_to_bf16u(u2.x); a1[1] = (short)f32_to_bf16u(u2.y);
      a1[2] = (short)f32_to_bf16u(u2.z); a1[3] = (short)f32_to_bf16u(u2.w);
      a1[4] = (short)f32_to_bf16u(u3.x); a1[5] = (short)f32_to_bf16u(u3.y);
      a1[6] = (short)f32_to_bf16u(u3.z); a1[7] = (short)f32_to_bf16u(u3.w);
    } else {
      const unsigned short* xr =
          (const unsigned short*)xin + (size_t)(row0 + f) * 64 + q * 8;
      a0 = *(const short8*)(xr);
      a1 = *(const short8*)(xr + 32);
    }
    float4v acc[4];
#pragma unroll
    for (int ct = 0; ct < 4; ct++) {
      float4v z = {0.f, 0.f, 0.f, 0.f};
      acc[ct] =
          __builtin_amdgcn_mfma_f32_16x16x32_bf16(a0, bfr[ct][0], z, 0, 0, 0);
      acc[ct] = __builtin_amdgcn_mfma_f32_16x16x32_bf16(a1, bfr[ct][1],
                                                        acc[ct], 0, 0, 0);
    }
    if (mode == 0) {
      float4 dv = *(const float4*)(dinv + row0 + q * 4);
      float d[4] = {dv.x, dv.y, dv.z, dv.w};
      unsigned short* op = (unsigned short*)out;
#pragma unroll
      for (int reg = 0; reg < 4; reg++) {
        size_t rb = (size_t)(row0 + q * 4 + reg) * 64 + f;
#pragma unroll
        for (int ct = 0; ct < 4; ct++)
          op[rb + 16 * ct] = f32_to_bf16u(d[reg] * acc[ct][reg]);
      }
    } else {
      int f32o = flags[0];
      float bv[4];
#pragma unroll
      for (int ct = 0; ct < 4; ct++) bv[ct] = bias[f + 16 * ct];
      if (f32o) {
        float* op = (float*)out;
#pragma unroll
        for (int reg = 0; reg < 4; reg++) {
          size_t rb = (size_t)(row0 + q * 4 + reg) * 64 + f;
#pragma unroll
          for (int ct = 0; ct < 4; ct++)
            op[rb + 16 * ct] = acc[ct][reg] + bv[ct];
        }
      } else {
        unsigned short* op = (unsigned short*)out;
#pragma unroll
        for (int reg = 0; reg < 4; reg++) {
          size_t rb = (size_t)(row0 + q * 4 + reg) * 64 + f;
#pragma unroll
          for (int ct = 0; ct < 4; ct++)
            op[rb + 16 * ct] = f32_to_bf16u(acc[ct][reg] + bv[ct]);
        }
      }
    }
  }
}

// ---------------- aggregation ----------------
// One wave per node. Quarter-split: 16 lanes x ushort4 = one 128B bf16 row;
// 4 edges per load instruction, unroll 4 => 16 gathers in flight per wave.
__global__ __launch_bounds__(256) void k_agg4(
    const unsigned short* __restrict__ hp, const int2* __restrict__ rowrange,
    const int* __restrict__ csr, const float* __restrict__ dinv,
    const float* __restrict__ biasf, unsigned short* __restrict__ xout,
    int n) {
  int lane = threadIdx.x & 63;
  int q = lane >> 4;  // quarter 0..3
  int f = lane & 15;  // ushort4 slot (features 4f..4f+3)
  int wid = threadIdx.x >> 6;
  int node = blockIdx.x * 4 + wid;
  if (node >= n) return;
  int un = __builtin_amdgcn_readfirstlane(node);

  int2 rr = rowrange[un];
  int s0 = rr.x;
  int s1 = rr.y;
  const ushort4* hp4 = (const ushort4*)hp;  // row stride = 16 ushort4

  float a0 = 0.f, a1 = 0.f, a2 = 0.f, a3 = 0.f;
  for (int base = s0; base < s1; base += 16) {
    int idx[4];
    bool m[4];
#pragma unroll
    for (int u = 0; u < 4; u++) {
      int i = base + 4 * u + q;
      m[u] = i < s1;
      idx[u] = m[u] ? i : s0;  // s0 valid: loop entered => s1 > s0
    }
    int srcs[4];
#pragma unroll
    for (int u = 0; u < 4; u++) srcs[u] = csr[idx[u]];
    ushort4 v[4];
#pragma unroll
    for (int u = 0; u < 4; u++) v[u] = hp4[(size_t)srcs[u] * 16 + f];
#pragma unroll
    for (int u = 0; u < 4; u++) {
      if (m[u]) {
        a0 += bf16u_to_f32(v[u].x);
        a1 += bf16u_to_f32(v[u].y);
        a2 += bf16u_to_f32(v[u].z);
        a3 += bf16u_to_f32(v[u].w);
      }
    }
  }
  a0 += __shfl_xor(a0, 16, 64); a0 += __shfl_xor(a0, 32, 64);
  a1 += __shfl_xor(a1, 16, 64); a1 += __shfl_xor(a1, 32, 64);
  a2 += __shfl_xor(a2, 16, 64); a2 += __shfl_xor(a2, 32, 64);
  a3 += __shfl_xor(a3, 16, 64); a3 += __shfl_xor(a3, 32, 64);

  if (q == 0) {
    ushort4 sv = hp4[(size_t)un * 16 + f];  // self loop
    a0 += bf16u_to_f32(sv.x);
    a1 += bf16u_to_f32(sv.y);
    a2 += bf16u_to_f32(sv.z);
    a3 += bf16u_to_f32(sv.w);
    float4 bv = ((const float4*)biasf)[f];
    float dv = dinv[un];
    ushort4 o;
    o.x = f32_to_bf16u(fmaxf(fmaf(dv, a0, bv.x), 0.f));
    o.y = f32_to_bf16u(fmaxf(fmaf(dv, a1, bv.y), 0.f));
    o.z = f32_to_bf16u(fmaxf(fmaf(dv, a2, bv.z), 0.f));
    o.w = f32_to_bf16u(fmaxf(fmaf(dv, a3, bv.w), 0.f));
    ((ushort4*)xout)[(size_t)un * 16 + f] = o;
  }
}

// ---------------- launch ----------------

extern "C" void kernel_launch(void* const* d_in, const int* in_sizes, int n_in,
                              void* d_out, int out_size, void* d_ws,
                              size_t ws_size, hipStream_t stream) {
  const void* x0 = d_in[0];
  const void* ei = d_in[1];
  const void* Ws = d_in[2];
  const void* bs = d_in[3];
  const void* Wout = d_in[4];
  const void* bout = d_in[5];

  const int N = in_sizes[0] / D;  // 100000
  const int E = in_sizes[1] / 2;  // 1000000
  const int NBUC = (N + BNODES - 1) >> BSHIFT;  // 391
  const int NT = N / 16;  // 6250 row tiles

  char* p = (char*)d_ws;
  auto alloc = [&](size_t bytes) {
    char* r = p;
    p += (bytes + 511) & ~(size_t)511;
    return r;
  };
  int* flags = (int*)alloc(8);
  int* bucket_cursor = (int*)alloc(512 * 4);
  int* packed = (int*)alloc((size_t)512 * BCAP * 4);
  int* csr = (int*)alloc((size_t)512 * BCAP * 4);
  int2* rowrange = (int2*)alloc((size_t)N * 8);
  float* dinv = (float*)alloc((size_t)N * 4);
  unsigned short* WT = (unsigned short*)alloc(4 * 4096 * 2);
  float* biasf = (float*)alloc(4 * 64 * 4);
  unsigned short* hp = (unsigned short*)alloc((size_t)N * D * 2);
  unsigned short* xb = (unsigned short*)alloc((size_t)N * D * 2);
  (void)ws_size;
  (void)n_in;
  (void)out_size;

  k_setup<<<1, 512, 0, stream>>>(Ws, Wout, bs, bout, ei, flags, WT, biasf,
                                 bucket_cursor);
  int ptiles = (E + PTILE - 1) / PTILE;
  k_partition<<<ptiles, 256, 0, stream>>>(ei, flags, bucket_cursor, packed, E);
  k_sort_csr<<<NBUC, 256, 0, stream>>>(packed, bucket_cursor, csr, rowrange,
                                       dinv, N);

  int gblocks = (NT + 3) / 4;  // ~1 tile per wave
  for (int l = 0; l < 3; ++l) {
    const void* xin = (l == 0) ? x0 : (const void*)xb;
    k_gemm<<<gblocks, 256, 0, stream>>>(xin, WT + l * 4096, dinv, nullptr, hp,
                                        flags, NT, 0, (l == 0) ? 1 : 0);
    k_agg4<<<(N + 3) / 4, 256, 0, stream>>>(hp, rowrange, csr, dinv,
                                            biasf + l * 64, xb, N);
  }
  k_gemm<<<gblocks, 256, 0, stream>>>(xb, WT + 3 * 4096, nullptr,
                                      biasf + 3 * 64, d_out, flags, NT, 1, 0);
}

// Round 8
// 289.038 us; speedup vs baseline: 5.6205x; 1.0436x over previous
//
#include <hip/hip_runtime.h>
#include <hip/hip_bf16.h>

#define D 64
#define BSHIFT 8           // 256 nodes per bucket
#define BNODES 256
#define BCAP 4096          // edge capacity per bucket region (exp 2558, +30 sigma)
#define PTILE 8192         // edges per partition tile

typedef __attribute__((ext_vector_type(8))) short short8;
typedef __attribute__((ext_vector_type(4))) float float4v;

// flags[0] = 1 if float tensors are fp32 (else bf16)
// flags[1] = 1 if edge_index is int64 (else int32)

__device__ __forceinline__ float bf16u_to_f32(unsigned short u) {
  union { unsigned int i; float f; } c;
  c.i = ((unsigned int)u) << 16;
  return c.f;
}

__device__ __forceinline__ unsigned short f32_to_bf16u(float f) {
  union { float f; unsigned int u; } c;
  c.f = f;
  unsigned int r = (c.u + 0x7fffu + ((c.u >> 16) & 1u)) >> 16;  // RNE
  return (unsigned short)r;
}

// ---------------- setup: probe dtypes + weight prep + cursor init ----------------

__global__ __launch_bounds__(512) void k_setup(
    const void* __restrict__ Ws, const void* __restrict__ Wout,
    const void* __restrict__ bs, const void* __restrict__ bout,
    const void* __restrict__ ei, int* __restrict__ flags,
    unsigned short* __restrict__ WT, float* __restrict__ biasf,
    int* __restrict__ bucket_cursor) {
  __shared__ int lf[2];
  int tid = threadIdx.x;
  if (tid < 64) {
    const unsigned short* wb = (const unsigned short*)Ws;
    bool big = false;
    for (int i = tid; i < 512; i += 64) {
      float v = bf16u_to_f32(wb[i]);
      if (!(fabsf(v) < 100.f)) big = true;  // NaN lands here too
    }
    int anybig = __any(big);
    const int* e32 = (const int*)ei;
    bool nz = (e32[2 * tid + 1] != 0);  // odd words of first 64 pairs
    int anynz = __any(nz);
    if (tid == 0) {
      lf[0] = anybig ? 1 : 0;  // huge magnitudes => data is actually fp32
      lf[1] = anynz ? 0 : 1;   // all-zero odd words => int64
      flags[0] = lf[0];
      flags[1] = lf[1];
    }
  }
  __syncthreads();
  int f32 = lf[0];

  bucket_cursor[tid] = tid * BCAP;  // 512 regions (391 used)

  // transpose 4 weight matrices into WT[l][n][k] (bf16)
  for (int i = tid; i < 4 * 4096; i += 512) {
    int l = i >> 12;
    int r = i & 4095;
    int k = r >> 6;
    int nn = r & 63;
    unsigned short v;
    if (l < 3) {
      v = f32 ? f32_to_bf16u(((const float*)Ws)[l * 4096 + r])
              : ((const unsigned short*)Ws)[l * 4096 + r];
    } else {
      v = f32 ? f32_to_bf16u(((const float*)Wout)[r])
              : ((const unsigned short*)Wout)[r];
    }
    WT[l * 4096 + nn * 64 + k] = v;
  }
  // biases -> fp32
  for (int i = tid; i < 4 * 64; i += 512) {
    int l = i >> 6;
    int j = i & 63;
    float v;
    if (l < 3)
      v = f32 ? ((const float*)bs)[l * 64 + j]
              : bf16u_to_f32(((const unsigned short*)bs)[l * 64 + j]);
    else
      v = f32 ? ((const float*)bout)[j]
              : bf16u_to_f32(((const unsigned short*)bout)[j]);
    biasf[i] = v;
  }
}

// ---------------- bucketed partition (fixed-capacity regions) ----------------

__global__ __launch_bounds__(256) void k_partition(
    const void* __restrict__ ei, const int* __restrict__ flags,
    int* __restrict__ bucket_cursor, int* __restrict__ packed, int e) {
  __shared__ int lhist[512];
  __shared__ int lbase[512];
  int tid = threadIdx.x;
  int t0 = blockIdx.x * PTILE;
  int tend = min(t0 + PTILE, e);
  if (t0 >= e) return;
  int i64 = flags[1];

  for (int b = tid; b < 512; b += 256) lhist[b] = 0;
  __syncthreads();

  if (i64) {
    const long long* dst = (const long long*)ei + e;
    for (int i = t0 + tid; i < tend; i += 256)
      atomicAdd(&lhist[((int)dst[i]) >> BSHIFT], 1);
  } else {
    const int* dst = (const int*)ei + e;
    for (int i = t0 + tid; i < tend; i += 256)
      atomicAdd(&lhist[dst[i] >> BSHIFT], 1);
  }
  __syncthreads();

  for (int b = tid; b < 512; b += 256) {
    int c = lhist[b];
    lbase[b] = c ? atomicAdd(&bucket_cursor[b], c) : 0;
    lhist[b] = 0;  // reuse as rank counter
  }
  __syncthreads();

  if (i64) {
    const long long* srcp = (const long long*)ei;
    const long long* dstp = srcp + e;
    for (int i = t0 + tid; i < tend; i += 256) {
      int s = (int)srcp[i];
      int d = (int)dstp[i];
      int b = d >> BSHIFT;
      int r = atomicAdd(&lhist[b], 1);
      packed[lbase[b] + r] = (s << BSHIFT) | (d & (BNODES - 1));
    }
  } else {
    const int* srcp = (const int*)ei;
    const int* dstp = srcp + e;
    for (int i = t0 + tid; i < tend; i += 256) {
      int s = srcp[i];
      int d = dstp[i];
      int b = d >> BSHIFT;
      int r = atomicAdd(&lhist[b], 1);
      packed[lbase[b] + r] = (s << BSHIFT) | (d & (BNODES - 1));
    }
  }
}

// One block per bucket: LDS counting sort -> per-node src list (grouped by
// dst) in the bucket's csr region, rowrange (beg,end), dinv.
__global__ __launch_bounds__(256) void k_sort_csr(
    const int* __restrict__ packed, const int* __restrict__ bucket_cursor,
    int* __restrict__ csr, int2* __restrict__ rowrange,
    float* __restrict__ dinv, int n) {
  __shared__ int lcnt[BNODES];
  __shared__ int lofs[BNODES];
  __shared__ int sbuf[BNODES];
  int tid = threadIdx.x;
  int bucket = blockIdx.x;
  int node0 = bucket << BSHIFT;
  int nodes = min(BNODES, n - node0);
  int s0 = bucket * BCAP;
  int s1 = bucket_cursor[bucket];  // region end after partition
  lcnt[tid] = 0;
  __syncthreads();
  for (int i = s0 + tid; i < s1; i += 256)
    atomicAdd(&lcnt[packed[i] & (BNODES - 1)], 1);
  __syncthreads();
  int v = lcnt[tid];
  sbuf[tid] = v;
  __syncthreads();
  for (int off = 1; off < BNODES; off <<= 1) {
    int tv = (tid >= off) ? sbuf[tid - off] : 0;
    __syncthreads();
    sbuf[tid] += tv;
    __syncthreads();
  }
  int excl = sbuf[tid] - v;
  lofs[tid] = excl;
  lcnt[tid] = 0;  // reuse as rank counter
  if (tid < nodes) {
    rowrange[node0 + tid] = make_int2(s0 + excl, s0 + excl + v);
    dinv[node0 + tid] = rsqrtf((float)(v + 1));  // +1 = self loop
  }
  __syncthreads();
  for (int i = s0 + tid; i < s1; i += 256) {
    int pk = packed[i];
    int ld = pk & (BNODES - 1);
    int r = atomicAdd(&lcnt[ld], 1);
    csr[s0 + lofs[ld] + r] = pk >> BSHIFT;
  }
}

// ---------------- z0 = dinv * x0 (bf16), handles fp32/bf16 input ----------------

__global__ __launch_bounds__(256) void k_scale(
    const void* __restrict__ x0, const int* __restrict__ flags,
    const float* __restrict__ dinv, ushort4* __restrict__ z, int n16) {
  int f32 = flags[0];
  int i = blockIdx.x * 256 + threadIdx.x;
  int stride = gridDim.x * 256;
  for (; i < n16; i += stride) {
    float d = dinv[i >> 4];
    ushort4 o;
    if (f32) {
      float4 v = ((const float4*)x0)[i];
      o.x = f32_to_bf16u(d * v.x);
      o.y = f32_to_bf16u(d * v.y);
      o.z = f32_to_bf16u(d * v.z);
      o.w = f32_to_bf16u(d * v.w);
    } else {
      ushort4 v = ((const ushort4*)x0)[i];
      o.x = f32_to_bf16u(d * bf16u_to_f32(v.x));
      o.y = f32_to_bf16u(d * bf16u_to_f32(v.y));
      o.z = f32_to_bf16u(d * bf16u_to_f32(v.z));
      o.w = f32_to_bf16u(d * bf16u_to_f32(v.w));
    }
    z[i] = o;
  }
}

// ---------------- fused layer: y = dinv_dst*(z_dst + sum z_src); out = relu(yW+b) ----------------
// One block per 16-node tile. Phase 1: each of 4 waves aggregates 4 nodes
// (quarter-split gather, 16 loads in flight), scales by dinv_dst, stores the
// bf16 y-row into LDS (row stride 80 ushorts => 16B-aligned, low conflict).
// Phase 2: wave w computes output cols w*16..w*16+15 with 2 MFMAs; epilogue
// relu(+bias); scale_out=1 -> write z' = dinv*relu (layers 0,1);
// scale_out=0 -> write x' = relu (layer 2).
__global__ __launch_bounds__(256) void k_fused(
    const unsigned short* __restrict__ z, const int2* __restrict__ rowrange,
    const int* __restrict__ csr, const float* __restrict__ dinv,
    const unsigned short* __restrict__ WT, const float* __restrict__ biasf,
    unsigned short* __restrict__ out, int n, int scale_out) {
  __shared__ unsigned short ybf[16 * 80];
  int tid = threadIdx.x;
  int lane = tid & 63;
  int w = tid >> 6;   // wave id = output col-tile ct
  int q = lane >> 4;  // quarter
  int f = lane & 15;

  // B-frags for this wave's column tile
  short8 b0 = *(const short8*)(WT + (size_t)(f + 16 * w) * 64 + q * 8);
  short8 b1 = *(const short8*)(WT + (size_t)(f + 16 * w) * 64 + 32 + q * 8);

  int row0 = blockIdx.x * 16;
  const ushort4* z4 = (const ushort4*)z;

  // phase 1: aggregate 4 nodes per wave
  for (int j = 0; j < 4; j++) {
    int nl = w * 4 + j;
    int un = row0 + nl;
    if (un >= n) break;
    int2 rr = rowrange[un];
    int s0 = rr.x;
    int s1 = rr.y;
    float a0 = 0.f, a1 = 0.f, a2 = 0.f, a3 = 0.f;
    for (int base = s0; base < s1; base += 16) {
      int idx[4];
      bool m[4];
#pragma unroll
      for (int u = 0; u < 4; u++) {
        int i = base + 4 * u + q;
        m[u] = i < s1;
        idx[u] = m[u] ? i : s0;
      }
      int srcs[4];
#pragma unroll
      for (int u = 0; u < 4; u++) srcs[u] = csr[idx[u]];
      ushort4 v[4];
#pragma unroll
      for (int u = 0; u < 4; u++) v[u] = z4[(size_t)srcs[u] * 16 + f];
#pragma unroll
      for (int u = 0; u < 4; u++) {
        if (m[u]) {
          a0 += bf16u_to_f32(v[u].x);
          a1 += bf16u_to_f32(v[u].y);
          a2 += bf16u_to_f32(v[u].z);
          a3 += bf16u_to_f32(v[u].w);
        }
      }
    }
    a0 += __shfl_xor(a0, 16, 64); a0 += __shfl_xor(a0, 32, 64);
    a1 += __shfl_xor(a1, 16, 64); a1 += __shfl_xor(a1, 32, 64);
    a2 += __shfl_xor(a2, 16, 64); a2 += __shfl_xor(a2, 32, 64);
    a3 += __shfl_xor(a3, 16, 64); a3 += __shfl_xor(a3, 32, 64);
    if (q == 0) {
      ushort4 sv = z4[(size_t)un * 16 + f];  // self loop (z_self)
      a0 += bf16u_to_f32(sv.x);
      a1 += bf16u_to_f32(sv.y);
      a2 += bf16u_to_f32(sv.z);
      a3 += bf16u_to_f32(sv.w);
      float dv = dinv[un];
      ushort4 o;
      o.x = f32_to_bf16u(dv * a0);
      o.y = f32_to_bf16u(dv * a1);
      o.z = f32_to_bf16u(dv * a2);
      o.w = f32_to_bf16u(dv * a3);
      *(ushort4*)&ybf[nl * 80 + 4 * f] = o;
    }
  }
  __syncthreads();

  // phase 2: MFMA yW for this wave's 16 columns
  short8 a0 = *(const short8*)&ybf[f * 80 + q * 8];
  short8 a1 = *(const short8*)&ybf[f * 80 + 32 + q * 8];
  float4v z4v = {0.f, 0.f, 0.f, 0.f};
  float4v acc = __builtin_amdgcn_mfma_f32_16x16x32_bf16(a0, b0, z4v, 0, 0, 0);
  acc = __builtin_amdgcn_mfma_f32_16x16x32_bf16(a1, b1, acc, 0, 0, 0);

  float bv = biasf[16 * w + f];
  if (scale_out) {
    float4 dv4 = *(const float4*)(dinv + row0 + q * 4);
    float d[4] = {dv4.x, dv4.y, dv4.z, dv4.w};
#pragma unroll
    for (int reg = 0; reg < 4; reg++) {
      int row = row0 + q * 4 + reg;
      if (row < n)
        out[(size_t)row * 64 + 16 * w + f] =
            f32_to_bf16u(d[reg] * fmaxf(acc[reg] + bv, 0.f));
    }
  } else {
#pragma unroll
    for (int reg = 0; reg < 4; reg++) {
      int row = row0 + q * 4 + reg;
      if (row < n)
        out[(size_t)row * 64 + 16 * w + f] =
            f32_to_bf16u(fmaxf(acc[reg] + bv, 0.f));
    }
  }
}

// ---------------- final projection GEMM ----------------
// out[N,64] = x @ Wout + bias; x bf16; store dtype per flags[0].
__global__ __launch_bounds__(256) void k_gemm_final(
    const unsigned short* __restrict__ xin,
    const unsigned short* __restrict__ WT, const float* __restrict__ bias,
    void* __restrict__ out, const int* __restrict__ flags, int ntiles) {
  int lane = threadIdx.x & 63;
  int wid = threadIdx.x >> 6;
  int f = lane & 15;
  int q = lane >> 4;

  short8 bfr[4][2];
#pragma unroll
  for (int ct = 0; ct < 4; ct++)
#pragma unroll
    for (int kt = 0; kt < 2; kt++)
      bfr[ct][kt] =
          *(const short8*)(WT + (size_t)(f + 16 * ct) * 64 + kt * 32 + q * 8);

  int wave = blockIdx.x * 4 + wid;
  int nwaves = gridDim.x * 4;
  for (int t = wave; t < ntiles; t += nwaves) {
    int row0 = t * 16;
    const unsigned short* xr = xin + (size_t)(row0 + f) * 64 + q * 8;
    short8 a0 = *(const short8*)(xr);
    short8 a1 = *(const short8*)(xr + 32);
    float4v acc[4];
#pragma unroll
    for (int ct = 0; ct < 4; ct++) {
      float4v z = {0.f, 0.f, 0.f, 0.f};
      acc[ct] =
          __builtin_amdgcn_mfma_f32_16x16x32_bf16(a0, bfr[ct][0], z, 0, 0, 0);
      acc[ct] = __builtin_amdgcn_mfma_f32_16x16x32_bf16(a1, bfr[ct][1],
                                                        acc[ct], 0, 0, 0);
    }
    int f32o = flags[0];
    float bv[4];
#pragma unroll
    for (int ct = 0; ct < 4; ct++) bv[ct] = bias[f + 16 * ct];
    if (f32o) {
      float* op = (float*)out;
#pragma unroll
      for (int reg = 0; reg < 4; reg++) {
        size_t rb = (size_t)(row0 + q * 4 + reg) * 64 + f;
#pragma unroll
        for (int ct = 0; ct < 4; ct++) op[rb + 16 * ct] = acc[ct][reg] + bv[ct];
      }
    } else {
      unsigned short* op = (unsigned short*)out;
#pragma unroll
      for (int reg = 0; reg < 4; reg++) {
        size_t rb = (size_t)(row0 + q * 4 + reg) * 64 + f;
#pragma unroll
        for (int ct = 0; ct < 4; ct++)
          op[rb + 16 * ct] = f32_to_bf16u(acc[ct][reg] + bv[ct]);
      }
    }
  }
}

// ---------------- launch ----------------

extern "C" void kernel_launch(void* const* d_in, const int* in_sizes, int n_in,
                              void* d_out, int out_size, void* d_ws,
                              size_t ws_size, hipStream_t stream) {
  const void* x0 = d_in[0];
  const void* ei = d_in[1];
  const void* Ws = d_in[2];
  const void* bs = d_in[3];
  const void* Wout = d_in[4];
  const void* bout = d_in[5];

  const int N = in_sizes[0] / D;  // 100000
  const int E = in_sizes[1] / 2;  // 1000000
  const int NBUC = (N + BNODES - 1) >> BSHIFT;  // 391
  const int NT = (N + 15) / 16;  // 6250 row tiles

  char* p = (char*)d_ws;
  auto alloc = [&](size_t bytes) {
    char* r = p;
    p += (bytes + 511) & ~(size_t)511;
    return r;
  };
  int* flags = (int*)alloc(8);
  int* bucket_cursor = (int*)alloc(512 * 4);
  int* packed = (int*)alloc((size_t)512 * BCAP * 4);
  int* csr = (int*)alloc((size_t)512 * BCAP * 4);
  int2* rowrange = (int2*)alloc((size_t)N * 8);
  float* dinv = (float*)alloc((size_t)N * 4);
  unsigned short* WT = (unsigned short*)alloc(4 * 4096 * 2);
  float* biasf = (float*)alloc(4 * 64 * 4);
  unsigned short* za = (unsigned short*)alloc((size_t)N * D * 2);
  unsigned short* zb = (unsigned short*)alloc((size_t)N * D * 2);
  (void)ws_size;
  (void)n_in;
  (void)out_size;

  k_setup<<<1, 512, 0, stream>>>(Ws, Wout, bs, bout, ei, flags, WT, biasf,
                                 bucket_cursor);
  int ptiles = (E + PTILE - 1) / PTILE;
  k_partition<<<ptiles, 256, 0, stream>>>(ei, flags, bucket_cursor, packed, E);
  k_sort_csr<<<NBUC, 256, 0, stream>>>(packed, bucket_cursor, csr, rowrange,
                                       dinv, N);
  k_scale<<<1024, 256, 0, stream>>>(x0, flags, dinv, (ushort4*)za, N * 16);

  // layer 0: za -> zb (z'), layer 1: zb -> za (z'), layer 2: za -> zb (x3)
  k_fused<<<NT, 256, 0, stream>>>(za, rowrange, csr, dinv, WT + 0 * 4096,
                                  biasf + 0 * 64, zb, N, 1);
  k_fused<<<NT, 256, 0, stream>>>(zb, rowrange, csr, dinv, WT + 1 * 4096,
                                  biasf + 1 * 64, za, N, 1);
  k_fused<<<NT, 256, 0, stream>>>(za, rowrange, csr, dinv, WT + 2 * 4096,
                                  biasf + 2 * 64, zb, N, 0);
  k_gemm_final<<<(NT + 3) / 4, 256, 0, stream>>>(zb, WT + 3 * 4096,
                                                 biasf + 3 * 64, d_out, flags,
                                                 NT);
}

// Round 9
// 270.044 us; speedup vs baseline: 6.0158x; 1.0703x over previous
//
#include <hip/hip_runtime.h>
#include <hip/hip_bf16.h>

#define D 64
#define BSHIFT 8           // 256 nodes per bucket
#define BNODES 256
#define BCAP 4096          // edge capacity per bucket region (exp 2558, +30 sigma)
#define PTILE 8192         // edges per partition tile

typedef __attribute__((ext_vector_type(8))) short short8;
typedef __attribute__((ext_vector_type(4))) float float4v;

// flags[0] = 1 if float tensors are fp32 (else bf16)
// flags[1] = 1 if edge_index is int64 (else int32)

__device__ __forceinline__ float bf16u_to_f32(unsigned short u) {
  union { unsigned int i; float f; } c;
  c.i = ((unsigned int)u) << 16;
  return c.f;
}

__device__ __forceinline__ unsigned short f32_to_bf16u(float f) {
  union { float f; unsigned int u; } c;
  c.f = f;
  unsigned int r = (c.u + 0x7fffu + ((c.u >> 16) & 1u)) >> 16;  // RNE
  return (unsigned short)r;
}

// ---------------- probe dtypes ----------------

__global__ void k_probe(const void* W, const void* ei, int* flags) {
  int lane = threadIdx.x & 63;
  const unsigned short* wb = (const unsigned short*)W;
  bool big = false;
  for (int i = lane; i < 512; i += 64) {
    float v = bf16u_to_f32(wb[i]);
    if (!(fabsf(v) < 100.f)) big = true;  // NaN lands here too
  }
  int anybig = __any(big);
  const int* e32 = (const int*)ei;
  bool nz = (e32[2 * lane + 1] != 0);  // odd words of first 64 pairs
  int anynz = __any(nz);
  if (threadIdx.x == 0) {
    flags[0] = anybig ? 1 : 0;  // huge magnitudes => data is actually fp32
    flags[1] = anynz ? 0 : 1;   // all-zero odd words => int64
  }
}

// ---------------- weight prep + cursor init (parallel) ----------------

__global__ __launch_bounds__(256) void k_prep(
    const void* __restrict__ Ws, const void* __restrict__ Wout,
    const void* __restrict__ bs, const void* __restrict__ bout,
    const int* __restrict__ flags, unsigned short* __restrict__ WT,
    float* __restrict__ biasf, int* __restrict__ bucket_cursor) {
  int f32 = flags[0];
  int gid = blockIdx.x * 256 + threadIdx.x;
  int stride = gridDim.x * 256;

  for (int i = gid; i < 512; i += stride) bucket_cursor[i] = i * BCAP;

  // transpose 4 weight matrices into WT[l][n][k] (bf16)
  for (int i = gid; i < 4 * 4096; i += stride) {
    int l = i >> 12;
    int r = i & 4095;
    int k = r >> 6;
    int nn = r & 63;
    unsigned short v;
    if (l < 3) {
      v = f32 ? f32_to_bf16u(((const float*)Ws)[l * 4096 + r])
              : ((const unsigned short*)Ws)[l * 4096 + r];
    } else {
      v = f32 ? f32_to_bf16u(((const float*)Wout)[r])
              : ((const unsigned short*)Wout)[r];
    }
    WT[l * 4096 + nn * 64 + k] = v;
  }
  // biases -> fp32
  for (int i = gid; i < 4 * 64; i += stride) {
    int l = i >> 6;
    int j = i & 63;
    float v;
    if (l < 3)
      v = f32 ? ((const float*)bs)[l * 64 + j]
              : bf16u_to_f32(((const unsigned short*)bs)[l * 64 + j]);
    else
      v = f32 ? ((const float*)bout)[j]
              : bf16u_to_f32(((const unsigned short*)bout)[j]);
    biasf[i] = v;
  }
}

// ---------------- bucketed partition (fixed-capacity regions) ----------------

__global__ __launch_bounds__(256) void k_partition(
    const void* __restrict__ ei, const int* __restrict__ flags,
    int* __restrict__ bucket_cursor, int* __restrict__ packed, int e) {
  __shared__ int lhist[512];
  __shared__ int lbase[512];
  int tid = threadIdx.x;
  int t0 = blockIdx.x * PTILE;
  int tend = min(t0 + PTILE, e);
  if (t0 >= e) return;
  int i64 = flags[1];

  for (int b = tid; b < 512; b += 256) lhist[b] = 0;
  __syncthreads();

  if (i64) {
    const long long* dst = (const long long*)ei + e;
    for (int i = t0 + tid; i < tend; i += 256)
      atomicAdd(&lhist[((int)dst[i]) >> BSHIFT], 1);
  } else {
    const int* dst = (const int*)ei + e;
    for (int i = t0 + tid; i < tend; i += 256)
      atomicAdd(&lhist[dst[i] >> BSHIFT], 1);
  }
  __syncthreads();

  for (int b = tid; b < 512; b += 256) {
    int c = lhist[b];
    lbase[b] = c ? atomicAdd(&bucket_cursor[b], c) : 0;
    lhist[b] = 0;  // reuse as rank counter
  }
  __syncthreads();

  if (i64) {
    const long long* srcp = (const long long*)ei;
    const long long* dstp = srcp + e;
    for (int i = t0 + tid; i < tend; i += 256) {
      int s = (int)srcp[i];
      int d = (int)dstp[i];
      int b = d >> BSHIFT;
      int r = atomicAdd(&lhist[b], 1);
      packed[lbase[b] + r] = (s << BSHIFT) | (d & (BNODES - 1));
    }
  } else {
    const int* srcp = (const int*)ei;
    const int* dstp = srcp + e;
    for (int i = t0 + tid; i < tend; i += 256) {
      int s = srcp[i];
      int d = dstp[i];
      int b = d >> BSHIFT;
      int r = atomicAdd(&lhist[b], 1);
      packed[lbase[b] + r] = (s << BSHIFT) | (d & (BNODES - 1));
    }
  }
}

// One block per bucket: LDS counting sort -> per-node src list (grouped by
// dst) in the bucket's csr region, rowrange (beg,end), dinv.
__global__ __launch_bounds__(256) void k_sort_csr(
    const int* __restrict__ packed, const int* __restrict__ bucket_cursor,
    int* __restrict__ csr, int2* __restrict__ rowrange,
    float* __restrict__ dinv, int n) {
  __shared__ int lcnt[BNODES];
  __shared__ int lofs[BNODES];
  __shared__ int sbuf[BNODES];
  int tid = threadIdx.x;
  int bucket = blockIdx.x;
  int node0 = bucket << BSHIFT;
  int nodes = min(BNODES, n - node0);
  int s0 = bucket * BCAP;
  int s1 = bucket_cursor[bucket];  // region end after partition
  lcnt[tid] = 0;
  __syncthreads();
  for (int i = s0 + tid; i < s1; i += 256)
    atomicAdd(&lcnt[packed[i] & (BNODES - 1)], 1);
  __syncthreads();
  int v = lcnt[tid];
  sbuf[tid] = v;
  __syncthreads();
  for (int off = 1; off < BNODES; off <<= 1) {
    int tv = (tid >= off) ? sbuf[tid - off] : 0;
    __syncthreads();
    sbuf[tid] += tv;
    __syncthreads();
  }
  int excl = sbuf[tid] - v;
  lofs[tid] = excl;
  lcnt[tid] = 0;  // reuse as rank counter
  if (tid < nodes) {
    rowrange[node0 + tid] = make_int2(s0 + excl, s0 + excl + v);
    dinv[node0 + tid] = rsqrtf((float)(v + 1));  // +1 = self loop
  }
  __syncthreads();
  for (int i = s0 + tid; i < s1; i += 256) {
    int pk = packed[i];
    int ld = pk & (BNODES - 1);
    int r = atomicAdd(&lcnt[ld], 1);
    csr[s0 + lofs[ld] + r] = pk >> BSHIFT;
  }
}

// ---------------- z0 = dinv * x0 (bf16), handles fp32/bf16 input ----------------

__global__ __launch_bounds__(256) void k_scale(
    const void* __restrict__ x0, const int* __restrict__ flags,
    const float* __restrict__ dinv, ushort4* __restrict__ z, int n16) {
  int f32 = flags[0];
  int i = blockIdx.x * 256 + threadIdx.x;
  int stride = gridDim.x * 256;
  for (; i < n16; i += stride) {
    float d = dinv[i >> 4];
    ushort4 o;
    if (f32) {
      float4 v = ((const float4*)x0)[i];
      o.x = f32_to_bf16u(d * v.x);
      o.y = f32_to_bf16u(d * v.y);
      o.z = f32_to_bf16u(d * v.z);
      o.w = f32_to_bf16u(d * v.w);
    } else {
      ushort4 v = ((const ushort4*)x0)[i];
      o.x = f32_to_bf16u(d * bf16u_to_f32(v.x));
      o.y = f32_to_bf16u(d * bf16u_to_f32(v.y));
      o.z = f32_to_bf16u(d * bf16u_to_f32(v.z));
      o.w = f32_to_bf16u(d * bf16u_to_f32(v.w));
    }
    z[i] = o;
  }
}

// ---------------- fused layer ----------------
// y = dinv_dst*(z_dst + sum z_src); out = relu(yW+b) [optionally * dinv].
// One block per 16-node tile; wave w owns nodes w*4..w*4+3 AND output cols
// w*16..w*16+15. Phase 1 issues ALL 4 nodes' first-16-edge gathers in two
// flat epochs (16 csr loads, then 16 row gathers = 64 edges in flight),
// accumulates in registers (self-loop folded into q==0 init), rare tail
// (deg>16, wave-uniform) loops. Merge quarters via shfl, y -> LDS (stride 80).
// Phase 2: 2 MFMAs for this wave's 16 output cols, epilogue, store.
__global__ __launch_bounds__(256) void k_fused(
    const unsigned short* __restrict__ z, const int2* __restrict__ rowrange,
    const int* __restrict__ csr, const float* __restrict__ dinv,
    const unsigned short* __restrict__ WT, const float* __restrict__ biasf,
    unsigned short* __restrict__ out, int n, int scale_out) {
  __shared__ unsigned short ybf[16 * 80];
  int tid = threadIdx.x;
  int lane = tid & 63;
  int w = tid >> 6;   // wave id = output col-tile
  int q = lane >> 4;  // quarter
  int f = lane & 15;

  // B-frags for this wave's column tile
  short8 b0 = *(const short8*)(WT + (size_t)(f + 16 * w) * 64 + q * 8);
  short8 b1 = *(const short8*)(WT + (size_t)(f + 16 * w) * 64 + 32 + q * 8);

  int row0 = blockIdx.x * 16;
  int base_node = row0 + w * 4;
  const ushort4* z4 = (const ushort4*)z;

  // --- phase 1: aggregate 4 nodes, batched ---
  int2 rr[4];
#pragma unroll
  for (int j = 0; j < 4; j++) rr[j] = rowrange[base_node + j];

  // self rows; count once => only quarter 0 seeds with self, others 0
  float ac[4][4];
#pragma unroll
  for (int j = 0; j < 4; j++) {
    ushort4 sv = z4[(size_t)(base_node + j) * 16 + f];
    ac[j][0] = (q == 0) ? bf16u_to_f32(sv.x) : 0.f;
    ac[j][1] = (q == 0) ? bf16u_to_f32(sv.y) : 0.f;
    ac[j][2] = (q == 0) ? bf16u_to_f32(sv.z) : 0.f;
    ac[j][3] = (q == 0) ? bf16u_to_f32(sv.w) : 0.f;
  }

  // first 16 edges of each node: all csr loads, then all gathers
  int srcs[16];
  bool mm[16];
#pragma unroll
  for (int j = 0; j < 4; j++) {
#pragma unroll
    for (int u = 0; u < 4; u++) {
      int i = rr[j].x + 4 * u + q;
      bool m = i < rr[j].y;
      mm[j * 4 + u] = m;
      srcs[j * 4 + u] = csr[m ? i : rr[j].x];
    }
  }
  ushort4 g[16];
#pragma unroll
  for (int t = 0; t < 16; t++) g[t] = z4[(size_t)srcs[t] * 16 + f];
#pragma unroll
  for (int j = 0; j < 4; j++) {
#pragma unroll
    for (int u = 0; u < 4; u++) {
      ushort4 v = g[j * 4 + u];
      if (mm[j * 4 + u]) {
        ac[j][0] += bf16u_to_f32(v.x);
        ac[j][1] += bf16u_to_f32(v.y);
        ac[j][2] += bf16u_to_f32(v.z);
        ac[j][3] += bf16u_to_f32(v.w);
      }
    }
  }

  // rare tail: deg > 16 (wave-uniform branch per node)
#pragma unroll
  for (int j = 0; j < 4; j++) {
    for (int base = rr[j].x + 16; base < rr[j].y; base += 16) {
      int ts[4];
      bool tm[4];
#pragma unroll
      for (int u = 0; u < 4; u++) {
        int i = base + 4 * u + q;
        tm[u] = i < rr[j].y;
        ts[u] = csr[tm[u] ? i : rr[j].x];
      }
      ushort4 tv[4];
#pragma unroll
      for (int u = 0; u < 4; u++) tv[u] = z4[(size_t)ts[u] * 16 + f];
#pragma unroll
      for (int u = 0; u < 4; u++) {
        if (tm[u]) {
          ac[j][0] += bf16u_to_f32(tv[u].x);
          ac[j][1] += bf16u_to_f32(tv[u].y);
          ac[j][2] += bf16u_to_f32(tv[u].z);
          ac[j][3] += bf16u_to_f32(tv[u].w);
        }
      }
    }
  }

  // merge quarters, scale by dinv_dst, write y rows to LDS
#pragma unroll
  for (int j = 0; j < 4; j++) {
#pragma unroll
    for (int c = 0; c < 4; c++) {
      ac[j][c] += __shfl_xor(ac[j][c], 16, 64);
      ac[j][c] += __shfl_xor(ac[j][c], 32, 64);
    }
  }
  if (q == 0) {
#pragma unroll
    for (int j = 0; j < 4; j++) {
      float dv = dinv[base_node + j];
      ushort4 o;
      o.x = f32_to_bf16u(dv * ac[j][0]);
      o.y = f32_to_bf16u(dv * ac[j][1]);
      o.z = f32_to_bf16u(dv * ac[j][2]);
      o.w = f32_to_bf16u(dv * ac[j][3]);
      *(ushort4*)&ybf[(w * 4 + j) * 80 + 4 * f] = o;
    }
  }
  __syncthreads();

  // --- phase 2: MFMA yW for this wave's 16 columns ---
  short8 a0 = *(const short8*)&ybf[f * 80 + q * 8];
  short8 a1 = *(const short8*)&ybf[f * 80 + 32 + q * 8];
  float4v zz = {0.f, 0.f, 0.f, 0.f};
  float4v acc = __builtin_amdgcn_mfma_f32_16x16x32_bf16(a0, b0, zz, 0, 0, 0);
  acc = __builtin_amdgcn_mfma_f32_16x16x32_bf16(a1, b1, acc, 0, 0, 0);

  float bv = biasf[16 * w + f];
  if (scale_out) {
    float4 dv4 = *(const float4*)(dinv + row0 + q * 4);
    float d[4] = {dv4.x, dv4.y, dv4.z, dv4.w};
#pragma unroll
    for (int reg = 0; reg < 4; reg++) {
      int row = row0 + q * 4 + reg;
      if (row < n)
        out[(size_t)row * 64 + 16 * w + f] =
            f32_to_bf16u(d[reg] * fmaxf(acc[reg] + bv, 0.f));
    }
  } else {
#pragma unroll
    for (int reg = 0; reg < 4; reg++) {
      int row = row0 + q * 4 + reg;
      if (row < n)
        out[(size_t)row * 64 + 16 * w + f] =
            f32_to_bf16u(fmaxf(acc[reg] + bv, 0.f));
    }
  }
}

// ---------------- final projection GEMM ----------------
// out[N,64] = x @ Wout + bias; x bf16; store dtype per flags[0].
__global__ __launch_bounds__(256) void k_gemm_final(
    const unsigned short* __restrict__ xin,
    const unsigned short* __restrict__ WT, const float* __restrict__ bias,
    void* __restrict__ out, const int* __restrict__ flags, int ntiles) {
  int lane = threadIdx.x & 63;
  int wid = threadIdx.x >> 6;
  int f = lane & 15;
  int q = lane >> 4;

  short8 bfr[4][2];
#pragma unroll
  for (int ct = 0; ct < 4; ct++)
#pragma unroll
    for (int kt = 0; kt < 2; kt++)
      bfr[ct][kt] =
          *(const short8*)(WT + (size_t)(f + 16 * ct) * 64 + kt * 32 + q * 8);

  int wave = blockIdx.x * 4 + wid;
  int nwaves = gridDim.x * 4;
  for (int t = wave; t < ntiles; t += nwaves) {
    int row0 = t * 16;
    const unsigned short* xr = xin + (size_t)(row0 + f) * 64 + q * 8;
    short8 a0 = *(const short8*)(xr);
    short8 a1 = *(const short8*)(xr + 32);
    float4v acc[4];
#pragma unroll
    for (int ct = 0; ct < 4; ct++) {
      float4v z = {0.f, 0.f, 0.f, 0.f};
      acc[ct] =
          __builtin_amdgcn_mfma_f32_16x16x32_bf16(a0, bfr[ct][0], z, 0, 0, 0);
      acc[ct] = __builtin_amdgcn_mfma_f32_16x16x32_bf16(a1, bfr[ct][1],
                                                        acc[ct], 0, 0, 0);
    }
    int f32o = flags[0];
    float bv[4];
#pragma unroll
    for (int ct = 0; ct < 4; ct++) bv[ct] = bias[f + 16 * ct];
    if (f32o) {
      float* op = (float*)out;
#pragma unroll
      for (int reg = 0; reg < 4; reg++) {
        size_t rb = (size_t)(row0 + q * 4 + reg) * 64 + f;
#pragma unroll
        for (int ct = 0; ct < 4; ct++) op[rb + 16 * ct] = acc[ct][reg] + bv[ct];
      }
    } else {
      unsigned short* op = (unsigned short*)out;
#pragma unroll
      for (int reg = 0; reg < 4; reg++) {
        size_t rb = (size_t)(row0 + q * 4 + reg) * 64 + f;
#pragma unroll
        for (int ct = 0; ct < 4; ct++)
          op[rb + 16 * ct] = f32_to_bf16u(acc[ct][reg] + bv[ct]);
      }
    }
  }
}

// ---------------- launch ----------------

extern "C" void kernel_launch(void* const* d_in, const int* in_sizes, int n_in,
                              void* d_out, int out_size, void* d_ws,
                              size_t ws_size, hipStream_t stream) {
  const void* x0 = d_in[0];
  const void* ei = d_in[1];
  const void* Ws = d_in[2];
  const void* bs = d_in[3];
  const void* Wout = d_in[4];
  const void* bout = d_in[5];

  const int N = in_sizes[0] / D;  // 100000
  const int E = in_sizes[1] / 2;  // 1000000
  const int NBUC = (N + BNODES - 1) >> BSHIFT;  // 391
  const int NT = (N + 15) / 16;  // 6250 row tiles

  char* p = (char*)d_ws;
  auto alloc = [&](size_t bytes) {
    char* r = p;
    p += (bytes + 511) & ~(size_t)511;
    return r;
  };
  int* flags = (int*)alloc(8);
  int* bucket_cursor = (int*)alloc(512 * 4);
  int* packed = (int*)alloc((size_t)512 * BCAP * 4);
  int* csr = (int*)alloc((size_t)512 * BCAP * 4);
  int2* rowrange = (int2*)alloc((size_t)N * 8);
  float* dinv = (float*)alloc((size_t)N * 4);
  unsigned short* WT = (unsigned short*)alloc(4 * 4096 * 2);
  float* biasf = (float*)alloc(4 * 64 * 4);
  unsigned short* za = (unsigned short*)alloc((size_t)N * D * 2);
  unsigned short* zb = (unsigned short*)alloc((size_t)N * D * 2);
  (void)ws_size;
  (void)n_in;
  (void)out_size;

  k_probe<<<1, 64, 0, stream>>>(Ws, ei, flags);
  k_prep<<<32, 256, 0, stream>>>(Ws, Wout, bs, bout, flags, WT, biasf,
                                 bucket_cursor);
  int ptiles = (E + PTILE - 1) / PTILE;
  k_partition<<<ptiles, 256, 0, stream>>>(ei, flags, bucket_cursor, packed, E);
  k_sort_csr<<<NBUC, 256, 0, stream>>>(packed, bucket_cursor, csr, rowrange,
                                       dinv, N);
  k_scale<<<1024, 256, 0, stream>>>(x0, flags, dinv, (ushort4*)za, N * 16);

  // layer 0: za -> zb (z'), layer 1: zb -> za (z'), layer 2: za -> zb (x3)
  k_fused<<<NT, 256, 0, stream>>>(za, rowrange, csr, dinv, WT + 0 * 4096,
                                  biasf + 0 * 64, zb, N, 1);
  k_fused<<<NT, 256, 0, stream>>>(zb, rowrange, csr, dinv, WT + 1 * 4096,
                                  biasf + 1 * 64, za, N, 1);
  k_fused<<<NT, 256, 0, stream>>>(za, rowrange, csr, dinv, WT + 2 * 4096,
                                  biasf + 2 * 64, zb, N, 0);
  k_gemm_final<<<(NT + 3) / 4, 256, 0, stream>>>(zb, WT + 3 * 4096,
                                                 biasf + 3 * 64, d_out, flags,
                                                 NT);
}

// Round 10
// 265.415 us; speedup vs baseline: 6.1207x; 1.0174x over previous
//
#include <hip/hip_runtime.h>
#include <hip/hip_bf16.h>

#define D 64
#define BSHIFT 8           // 256 nodes per bucket
#define BNODES 256
#define BCAP 4096          // edge capacity per bucket region (exp 2558, +30 sigma)
#define PTILE 2048         // edges per partition tile (489 blocks -> full CU coverage)

typedef __attribute__((ext_vector_type(8))) short short8;
typedef __attribute__((ext_vector_type(4))) float float4v;

// flags[0] = 1 if float tensors are fp32 (else bf16)
// flags[1] = 1 if edge_index is int64 (else int32)

__device__ __forceinline__ float bf16u_to_f32(unsigned short u) {
  union { unsigned int i; float f; } c;
  c.i = ((unsigned int)u) << 16;
  return c.f;
}

__device__ __forceinline__ unsigned short f32_to_bf16u(float f) {
  union { float f; unsigned int u; } c;
  c.f = f;
  unsigned int r = (c.u + 0x7fffu + ((c.u >> 16) & 1u)) >> 16;  // RNE
  return (unsigned short)r;
}

// ---------------- probe dtypes ----------------

__global__ void k_probe(const void* W, const void* ei, int* flags) {
  int lane = threadIdx.x & 63;
  const unsigned short* wb = (const unsigned short*)W;
  bool big = false;
  for (int i = lane; i < 512; i += 64) {
    float v = bf16u_to_f32(wb[i]);
    if (!(fabsf(v) < 100.f)) big = true;  // NaN lands here too
  }
  int anybig = __any(big);
  const int* e32 = (const int*)ei;
  bool nz = (e32[2 * lane + 1] != 0);  // odd words of first 64 pairs
  int anynz = __any(nz);
  if (threadIdx.x == 0) {
    flags[0] = anybig ? 1 : 0;  // huge magnitudes => data is actually fp32
    flags[1] = anynz ? 0 : 1;   // all-zero odd words => int64
  }
}

// ---------------- weight prep + cursor init (parallel) ----------------

__global__ __launch_bounds__(256) void k_prep(
    const void* __restrict__ Ws, const void* __restrict__ Wout,
    const void* __restrict__ bs, const void* __restrict__ bout,
    const int* __restrict__ flags, unsigned short* __restrict__ WT,
    float* __restrict__ biasf, int* __restrict__ bucket_cursor) {
  int f32 = flags[0];
  int gid = blockIdx.x * 256 + threadIdx.x;
  int stride = gridDim.x * 256;

  for (int i = gid; i < 512; i += stride) bucket_cursor[i] = i * BCAP;

  // transpose 4 weight matrices into WT[l][n][k] (bf16)
  for (int i = gid; i < 4 * 4096; i += stride) {
    int l = i >> 12;
    int r = i & 4095;
    int k = r >> 6;
    int nn = r & 63;
    unsigned short v;
    if (l < 3) {
      v = f32 ? f32_to_bf16u(((const float*)Ws)[l * 4096 + r])
              : ((const unsigned short*)Ws)[l * 4096 + r];
    } else {
      v = f32 ? f32_to_bf16u(((const float*)Wout)[r])
              : ((const unsigned short*)Wout)[r];
    }
    WT[l * 4096 + nn * 64 + k] = v;
  }
  // biases -> fp32
  for (int i = gid; i < 4 * 64; i += stride) {
    int l = i >> 6;
    int j = i & 63;
    float v;
    if (l < 3)
      v = f32 ? ((const float*)bs)[l * 64 + j]
              : bf16u_to_f32(((const unsigned short*)bs)[l * 64 + j]);
    else
      v = f32 ? ((const float*)bout)[j]
              : bf16u_to_f32(((const unsigned short*)bout)[j]);
    biasf[i] = v;
  }
}

// ---------------- bucketed partition (fixed-capacity regions) ----------------

__global__ __launch_bounds__(256) void k_partition(
    const void* __restrict__ ei, const int* __restrict__ flags,
    int* __restrict__ bucket_cursor, int* __restrict__ packed, int e) {
  __shared__ int lhist[512];
  __shared__ int lbase[512];
  int tid = threadIdx.x;
  int t0 = blockIdx.x * PTILE;
  int tend = min(t0 + PTILE, e);
  if (t0 >= e) return;
  int i64 = flags[1];

  for (int b = tid; b < 512; b += 256) lhist[b] = 0;
  __syncthreads();

  if (i64) {
    const long long* dst = (const long long*)ei + e;
    for (int i = t0 + tid; i < tend; i += 256)
      atomicAdd(&lhist[((int)dst[i]) >> BSHIFT], 1);
  } else {
    const int* dst = (const int*)ei + e;
    for (int i = t0 + tid; i < tend; i += 256)
      atomicAdd(&lhist[dst[i] >> BSHIFT], 1);
  }
  __syncthreads();

  for (int b = tid; b < 512; b += 256) {
    int c = lhist[b];
    lbase[b] = c ? atomicAdd(&bucket_cursor[b], c) : 0;
    lhist[b] = 0;  // reuse as rank counter
  }
  __syncthreads();

  if (i64) {
    const long long* srcp = (const long long*)ei;
    const long long* dstp = srcp + e;
    for (int i = t0 + tid; i < tend; i += 256) {
      int s = (int)srcp[i];
      int d = (int)dstp[i];
      int b = d >> BSHIFT;
      int r = atomicAdd(&lhist[b], 1);
      packed[lbase[b] + r] = (s << BSHIFT) | (d & (BNODES - 1));
    }
  } else {
    const int* srcp = (const int*)ei;
    const int* dstp = srcp + e;
    for (int i = t0 + tid; i < tend; i += 256) {
      int s = srcp[i];
      int d = dstp[i];
      int b = d >> BSHIFT;
      int r = atomicAdd(&lhist[b], 1);
      packed[lbase[b] + r] = (s << BSHIFT) | (d & (BNODES - 1));
    }
  }
}

// One block per bucket: LDS counting sort -> per-node src list (grouped by
// dst) in the bucket's csr region, rowrange (beg,end), dinv.
__global__ __launch_bounds__(256) void k_sort_csr(
    const int* __restrict__ packed, const int* __restrict__ bucket_cursor,
    int* __restrict__ csr, int2* __restrict__ rowrange,
    float* __restrict__ dinv, int n) {
  __shared__ int lcnt[BNODES];
  __shared__ int lofs[BNODES];
  __shared__ int sbuf[BNODES];
  int tid = threadIdx.x;
  int bucket = blockIdx.x;
  int node0 = bucket << BSHIFT;
  int nodes = min(BNODES, n - node0);
  int s0 = bucket * BCAP;
  int s1 = bucket_cursor[bucket];  // region end after partition
  lcnt[tid] = 0;
  __syncthreads();
  for (int i = s0 + tid; i < s1; i += 256)
    atomicAdd(&lcnt[packed[i] & (BNODES - 1)], 1);
  __syncthreads();
  int v = lcnt[tid];
  sbuf[tid] = v;
  __syncthreads();
  for (int off = 1; off < BNODES; off <<= 1) {
    int tv = (tid >= off) ? sbuf[tid - off] : 0;
    __syncthreads();
    sbuf[tid] += tv;
    __syncthreads();
  }
  int excl = sbuf[tid] - v;
  lofs[tid] = excl;
  lcnt[tid] = 0;  // reuse as rank counter
  if (tid < nodes) {
    rowrange[node0 + tid] = make_int2(s0 + excl, s0 + excl + v);
    dinv[node0 + tid] = rsqrtf((float)(v + 1));  // +1 = self loop
  }
  __syncthreads();
  for (int i = s0 + tid; i < s1; i += 256) {
    int pk = packed[i];
    int ld = pk & (BNODES - 1);
    int r = atomicAdd(&lcnt[ld], 1);
    csr[s0 + lofs[ld] + r] = pk >> BSHIFT;
  }
}

// ---------------- z0 = dinv * x0 (bf16), handles fp32/bf16 input ----------------

__global__ __launch_bounds__(256) void k_scale(
    const void* __restrict__ x0, const int* __restrict__ flags,
    const float* __restrict__ dinv, ushort4* __restrict__ z, int n16) {
  int f32 = flags[0];
  int i = blockIdx.x * 256 + threadIdx.x;
  int stride = gridDim.x * 256;
  for (; i < n16; i += stride) {
    float d = dinv[i >> 4];
    ushort4 o;
    if (f32) {
      float4 v = ((const float4*)x0)[i];
      o.x = f32_to_bf16u(d * v.x);
      o.y = f32_to_bf16u(d * v.y);
      o.z = f32_to_bf16u(d * v.z);
      o.w = f32_to_bf16u(d * v.w);
    } else {
      ushort4 v = ((const ushort4*)x0)[i];
      o.x = f32_to_bf16u(d * bf16u_to_f32(v.x));
      o.y = f32_to_bf16u(d * bf16u_to_f32(v.y));
      o.z = f32_to_bf16u(d * bf16u_to_f32(v.z));
      o.w = f32_to_bf16u(d * bf16u_to_f32(v.w));
    }
    z[i] = o;
  }
}

// ---------------- fused layer ----------------
// y = dinv_dst*(z_dst + sum z_src); out = relu(yW+b) [optionally * dinv].
// One block per 16-node tile; wave w owns nodes w*4..w*4+3 AND output cols
// w*16..w*16+15. Phase 1 issues ALL 4 nodes' first-16-edge gathers in two
// flat epochs (16 csr loads, then 16 row gathers = 64 edges in flight).
// __launch_bounds__(256,4) caps VGPR at 128 so the 16 ushort4 flight regs
// (32 VGPRs) + srcs (16) + acc (16) can ALL stay live — round-9's 48-VGPR
// allocation provably re-serialized the epochs. Rare tail (deg>16) loops.
// Merge quarters via shfl, y -> LDS (stride 80). Phase 2: 2 MFMAs.
__global__ __launch_bounds__(256, 4) void k_fused(
    const unsigned short* __restrict__ z, const int2* __restrict__ rowrange,
    const int* __restrict__ csr, const float* __restrict__ dinv,
    const unsigned short* __restrict__ WT, const float* __restrict__ biasf,
    unsigned short* __restrict__ out, int n, int scale_out) {
  __shared__ unsigned short ybf[16 * 80];
  int tid = threadIdx.x;
  int lane = tid & 63;
  int w = tid >> 6;   // wave id = output col-tile
  int q = lane >> 4;  // quarter
  int f = lane & 15;

  // B-frags for this wave's column tile
  short8 b0 = *(const short8*)(WT + (size_t)(f + 16 * w) * 64 + q * 8);
  short8 b1 = *(const short8*)(WT + (size_t)(f + 16 * w) * 64 + 32 + q * 8);

  int row0 = blockIdx.x * 16;
  int base_node = row0 + w * 4;
  const ushort4* z4 = (const ushort4*)z;

  // --- phase 1: aggregate 4 nodes, batched ---
  int2 rr[4];
#pragma unroll
  for (int j = 0; j < 4; j++) rr[j] = rowrange[base_node + j];

  // self rows; count once => only quarter 0 seeds with self, others 0
  float ac[4][4];
#pragma unroll
  for (int j = 0; j < 4; j++) {
    ushort4 sv = z4[(size_t)(base_node + j) * 16 + f];
    ac[j][0] = (q == 0) ? bf16u_to_f32(sv.x) : 0.f;
    ac[j][1] = (q == 0) ? bf16u_to_f32(sv.y) : 0.f;
    ac[j][2] = (q == 0) ? bf16u_to_f32(sv.z) : 0.f;
    ac[j][3] = (q == 0) ? bf16u_to_f32(sv.w) : 0.f;
  }

  // first 16 edges of each node: all csr loads, then all gathers
  int srcs[16];
  bool mm[16];
#pragma unroll
  for (int j = 0; j < 4; j++) {
#pragma unroll
    for (int u = 0; u < 4; u++) {
      int i = rr[j].x + 4 * u + q;
      bool m = i < rr[j].y;
      mm[j * 4 + u] = m;
      srcs[j * 4 + u] = csr[m ? i : rr[j].x];
    }
  }
  ushort4 g[16];
#pragma unroll
  for (int t = 0; t < 16; t++) g[t] = z4[(size_t)srcs[t] * 16 + f];
#pragma unroll
  for (int j = 0; j < 4; j++) {
#pragma unroll
    for (int u = 0; u < 4; u++) {
      ushort4 v = g[j * 4 + u];
      if (mm[j * 4 + u]) {
        ac[j][0] += bf16u_to_f32(v.x);
        ac[j][1] += bf16u_to_f32(v.y);
        ac[j][2] += bf16u_to_f32(v.z);
        ac[j][3] += bf16u_to_f32(v.w);
      }
    }
  }

  // rare tail: deg > 16 (wave-uniform branch per node)
#pragma unroll
  for (int j = 0; j < 4; j++) {
    for (int base = rr[j].x + 16; base < rr[j].y; base += 16) {
      int ts[4];
      bool tm[4];
#pragma unroll
      for (int u = 0; u < 4; u++) {
        int i = base + 4 * u + q;
        tm[u] = i < rr[j].y;
        ts[u] = csr[tm[u] ? i : rr[j].x];
      }
      ushort4 tv[4];
#pragma unroll
      for (int u = 0; u < 4; u++) tv[u] = z4[(size_t)ts[u] * 16 + f];
#pragma unroll
      for (int u = 0; u < 4; u++) {
        if (tm[u]) {
          ac[j][0] += bf16u_to_f32(tv[u].x);
          ac[j][1] += bf16u_to_f32(tv[u].y);
          ac[j][2] += bf16u_to_f32(tv[u].z);
          ac[j][3] += bf16u_to_f32(tv[u].w);
        }
      }
    }
  }

  // merge quarters, scale by dinv_dst, write y rows to LDS
#pragma unroll
  for (int j = 0; j < 4; j++) {
#pragma unroll
    for (int c = 0; c < 4; c++) {
      ac[j][c] += __shfl_xor(ac[j][c], 16, 64);
      ac[j][c] += __shfl_xor(ac[j][c], 32, 64);
    }
  }
  if (q == 0) {
#pragma unroll
    for (int j = 0; j < 4; j++) {
      float dv = dinv[base_node + j];
      ushort4 o;
      o.x = f32_to_bf16u(dv * ac[j][0]);
      o.y = f32_to_bf16u(dv * ac[j][1]);
      o.z = f32_to_bf16u(dv * ac[j][2]);
      o.w = f32_to_bf16u(dv * ac[j][3]);
      *(ushort4*)&ybf[(w * 4 + j) * 80 + 4 * f] = o;
    }
  }
  __syncthreads();

  // --- phase 2: MFMA yW for this wave's 16 columns ---
  short8 a0 = *(const short8*)&ybf[f * 80 + q * 8];
  short8 a1 = *(const short8*)&ybf[f * 80 + 32 + q * 8];
  float4v zz = {0.f, 0.f, 0.f, 0.f};
  float4v acc = __builtin_amdgcn_mfma_f32_16x16x32_bf16(a0, b0, zz, 0, 0, 0);
  acc = __builtin_amdgcn_mfma_f32_16x16x32_bf16(a1, b1, acc, 0, 0, 0);

  float bv = biasf[16 * w + f];
  if (scale_out) {
    float4 dv4 = *(const float4*)(dinv + row0 + q * 4);
    float d[4] = {dv4.x, dv4.y, dv4.z, dv4.w};
#pragma unroll
    for (int reg = 0; reg < 4; reg++) {
      int row = row0 + q * 4 + reg;
      if (row < n)
        out[(size_t)row * 64 + 16 * w + f] =
            f32_to_bf16u(d[reg] * fmaxf(acc[reg] + bv, 0.f));
    }
  } else {
#pragma unroll
    for (int reg = 0; reg < 4; reg++) {
      int row = row0 + q * 4 + reg;
      if (row < n)
        out[(size_t)row * 64 + 16 * w + f] =
            f32_to_bf16u(fmaxf(acc[reg] + bv, 0.f));
    }
  }
}

// ---------------- final projection GEMM ----------------
// out[N,64] = x @ Wout + bias; x bf16; store dtype per flags[0].
__global__ __launch_bounds__(256) void k_gemm_final(
    const unsigned short* __restrict__ xin,
    const unsigned short* __restrict__ WT, const float* __restrict__ bias,
    void* __restrict__ out, const int* __restrict__ flags, int ntiles) {
  int lane = threadIdx.x & 63;
  int wid = threadIdx.x >> 6;
  int f = lane & 15;
  int q = lane >> 4;

  short8 bfr[4][2];
#pragma unroll
  for (int ct = 0; ct < 4; ct++)
#pragma unroll
    for (int kt = 0; kt < 2; kt++)
      bfr[ct][kt] =
          *(const short8*)(WT + (size_t)(f + 16 * ct) * 64 + kt * 32 + q * 8);

  int wave = blockIdx.x * 4 + wid;
  int nwaves = gridDim.x * 4;
  for (int t = wave; t < ntiles; t += nwaves) {
    int row0 = t * 16;
    const unsigned short* xr = xin + (size_t)(row0 + f) * 64 + q * 8;
    short8 a0 = *(const short8*)(xr);
    short8 a1 = *(const short8*)(xr + 32);
    float4v acc[4];
#pragma unroll
    for (int ct = 0; ct < 4; ct++) {
      float4v z = {0.f, 0.f, 0.f, 0.f};
      acc[ct] =
          __builtin_amdgcn_mfma_f32_16x16x32_bf16(a0, bfr[ct][0], z, 0, 0, 0);
      acc[ct] = __builtin_amdgcn_mfma_f32_16x16x32_bf16(a1, bfr[ct][1],
                                                        acc[ct], 0, 0, 0);
    }
    int f32o = flags[0];
    float bv[4];
#pragma unroll
    for (int ct = 0; ct < 4; ct++) bv[ct] = bias[f + 16 * ct];
    if (f32o) {
      float* op = (float*)out;
#pragma unroll
      for (int reg = 0; reg < 4; reg++) {
        size_t rb = (size_t)(row0 + q * 4 + reg) * 64 + f;
#pragma unroll
        for (int ct = 0; ct < 4; ct++) op[rb + 16 * ct] = acc[ct][reg] + bv[ct];
      }
    } else {
      unsigned short* op = (unsigned short*)out;
#pragma unroll
      for (int reg = 0; reg < 4; reg++) {
        size_t rb = (size_t)(row0 + q * 4 + reg) * 64 + f;
#pragma unroll
        for (int ct = 0; ct < 4; ct++)
          op[rb + 16 * ct] = f32_to_bf16u(acc[ct][reg] + bv[ct]);
      }
    }
  }
}

// ---------------- launch ----------------

extern "C" void kernel_launch(void* const* d_in, const int* in_sizes, int n_in,
                              void* d_out, int out_size, void* d_ws,
                              size_t ws_size, hipStream_t stream) {
  const void* x0 = d_in[0];
  const void* ei = d_in[1];
  const void* Ws = d_in[2];
  const void* bs = d_in[3];
  const void* Wout = d_in[4];
  const void* bout = d_in[5];

  const int N = in_sizes[0] / D;  // 100000
  const int E = in_sizes[1] / 2;  // 1000000
  const int NBUC = (N + BNODES - 1) >> BSHIFT;  // 391
  const int NT = (N + 15) / 16;  // 6250 row tiles

  char* p = (char*)d_ws;
  auto alloc = [&](size_t bytes) {
    char* r = p;
    p += (bytes + 511) & ~(size_t)511;
    return r;
  };
  int* flags = (int*)alloc(8);
  int* bucket_cursor = (int*)alloc(512 * 4);
  int* packed = (int*)alloc((size_t)512 * BCAP * 4);
  int* csr = (int*)alloc((size_t)512 * BCAP * 4);
  int2* rowrange = (int2*)alloc((size_t)N * 8);
  float* dinv = (float*)alloc((size_t)N * 4);
  unsigned short* WT = (unsigned short*)alloc(4 * 4096 * 2);
  float* biasf = (float*)alloc(4 * 64 * 4);
  unsigned short* za = (unsigned short*)alloc((size_t)N * D * 2);
  unsigned short* zb = (unsigned short*)alloc((size_t)N * D * 2);
  (void)ws_size;
  (void)n_in;
  (void)out_size;

  k_probe<<<1, 64, 0, stream>>>(Ws, ei, flags);
  k_prep<<<32, 256, 0, stream>>>(Ws, Wout, bs, bout, flags, WT, biasf,
                                 bucket_cursor);
  int ptiles = (E + PTILE - 1) / PTILE;
  k_partition<<<ptiles, 256, 0, stream>>>(ei, flags, bucket_cursor, packed, E);
  k_sort_csr<<<NBUC, 256, 0, stream>>>(packed, bucket_cursor, csr, rowrange,
                                       dinv, N);
  k_scale<<<1024, 256, 0, stream>>>(x0, flags, dinv, (ushort4*)za, N * 16);

  // layer 0: za -> zb (z'), layer 1: zb -> za (z'), layer 2: za -> zb (x3)
  k_fused<<<NT, 256, 0, stream>>>(za, rowrange, csr, dinv, WT + 0 * 4096,
                                  biasf + 0 * 64, zb, N, 1);
  k_fused<<<NT, 256, 0, stream>>>(zb, rowrange, csr, dinv, WT + 1 * 4096,
                                  biasf + 1 * 64, za, N, 1);
  k_fused<<<NT, 256, 0, stream>>>(za, rowrange, csr, dinv, WT + 2 * 4096,
                                  biasf + 2 * 64, zb, N, 0);
  k_gemm_final<<<(NT + 3) / 4, 256, 0, stream>>>(zb, WT + 3 * 4096,
                                                 biasf + 3 * 64, d_out, flags,
                                                 NT);
}